// Round 1
// baseline (1441.443 us; speedup 1.0000x reference)
//
#include <hip/hip_runtime.h>

#define D 128
#define MAXN 0.996f            // (1 - BALL_EPS) / sqrt(c), c = 1
#define MINN 1e-15f
#define ARTANH_MAX (1.0f - 1e-7f)
#define MAX_NORM 1e6f

__device__ __forceinline__ float wave_sum(float v) {
#pragma unroll
    for (int o = 32; o > 0; o >>= 1) v += __shfl_xor(v, o, 64);
    return v;
}

__device__ __forceinline__ float artanh_clip(float x) {
    x = fminf(fmaxf(x, -ARTANH_MAX), ARTANH_MAX);
    return 0.5f * logf((1.0f + x) / (1.0f - x));
}

// ---------------- GEMM: mx[i][j] = sum_k x[i][k] * W[j][k] ----------------
// 32-row x 128-col tile per block, BK=32, 4x4 register blocking.
__global__ __launch_bounds__(256)
void gemm_kernel(const float* __restrict__ X, const float* __restrict__ W,
                 float* __restrict__ MX, int N)
{
    __shared__ float xs[32][36];    // xs[k][r] (transposed), padded
    __shared__ float wl[32][132];   // wl[k][c], padded
    const int tid = threadIdx.x;
    const int row0 = blockIdx.x * 32;
    const int ct = tid & 31;        // col group: cols ct*4..+3
    const int rt = tid >> 5;        // row group: rows rt*4..+3
    float acc[4][4] = {{0.f}};

    for (int k0 = 0; k0 < D; k0 += 32) {
        {
            int r = tid >> 3;
            int kq = (tid & 7) * 4;
            int rr = row0 + r;
            float4 v = make_float4(0.f, 0.f, 0.f, 0.f);
            if (rr < N) v = *(const float4*)(X + (size_t)rr * D + k0 + kq);
            xs[kq + 0][r] = v.x; xs[kq + 1][r] = v.y;
            xs[kq + 2][r] = v.z; xs[kq + 3][r] = v.w;
        }
        {
            int c = tid >> 1;
            int kh = (tid & 1) * 16;
            const float* wp = W + (size_t)c * D + k0 + kh;
#pragma unroll
            for (int i = 0; i < 16; i += 4) {
                float4 v = *(const float4*)(wp + i);
                wl[kh + i + 0][c] = v.x; wl[kh + i + 1][c] = v.y;
                wl[kh + i + 2][c] = v.z; wl[kh + i + 3][c] = v.w;
            }
        }
        __syncthreads();
#pragma unroll
        for (int k = 0; k < 32; ++k) {
            float4 a = *(const float4*)&xs[k][rt * 4];
            float4 b = *(const float4*)&wl[k][ct * 4];
            acc[0][0] += a.x * b.x; acc[0][1] += a.x * b.y; acc[0][2] += a.x * b.z; acc[0][3] += a.x * b.w;
            acc[1][0] += a.y * b.x; acc[1][1] += a.y * b.y; acc[1][2] += a.y * b.z; acc[1][3] += a.y * b.w;
            acc[2][0] += a.z * b.x; acc[2][1] += a.z * b.y; acc[2][2] += a.z * b.z; acc[2][3] += a.z * b.w;
            acc[3][0] += a.w * b.x; acc[3][1] += a.w * b.y; acc[3][2] += a.w * b.z; acc[3][3] += a.w * b.w;
        }
        __syncthreads();
    }
#pragma unroll
    for (int i = 0; i < 4; ++i) {
        int rr = row0 + rt * 4 + i;
        if (rr < N) {
            float4 o = make_float4(acc[i][0], acc[i][1], acc[i][2], acc[i][3]);
            *(float4*)(MX + (size_t)rr * D + ct * 4) = o;
        }
    }
}

// ------- rowA: fused mobius_matvec scale + proj + bias mobius_add + proj + logmap0 -------
// One 64-lane wave per row, 2 floats per lane. Writes x_tangent over MX in place.
__global__ __launch_bounds__(256)
void rowA_kernel(const float* __restrict__ X, float* __restrict__ MX,
                 const float* __restrict__ bias, int N)
{
    int row = blockIdx.x * 4 + (threadIdx.x >> 6);
    int lane = threadIdx.x & 63;
    if (row >= N) return;
    const float2 xv = ((const float2*)(X + (size_t)row * D))[lane];
    float2 mv = ((float2*)(MX + (size_t)row * D))[lane];
    const float2 bv = ((const float2*)bias)[lane];

    // mobius_matvec tail
    float xn  = fmaxf(sqrtf(wave_sum(xv.x * xv.x + xv.y * xv.y)), MINN);
    float mxn = fmaxf(sqrtf(wave_sum(mv.x * mv.x + mv.y * mv.y)), MINN);
    float sc = tanhf(mxn / xn * artanh_clip(xn)) / mxn;
    float r0 = sc * mv.x, r1 = sc * mv.y;
    if (__all(mv.x == 0.0f && mv.y == 0.0f)) { r0 = 0.0f; r1 = 0.0f; }
    // proj
    float rn = fmaxf(sqrtf(wave_sum(r0 * r0 + r1 * r1)), MINN);
    if (rn > MAXN) { float f = MAXN / rn; r0 *= f; r1 *= f; }
    // hyp_bias = proj(expmap0(bias))
    float bn = fmaxf(sqrtf(wave_sum(bv.x * bv.x + bv.y * bv.y)), MINN);
    float bs = tanhf(bn) / bn;
    float b0 = bs * bv.x, b1 = bs * bv.y;
    float hbn = fmaxf(sqrtf(wave_sum(b0 * b0 + b1 * b1)), MINN);
    if (hbn > MAXN) { float f = MAXN / hbn; b0 *= f; b1 *= f; }
    // mobius_add(r, b)
    float x2 = wave_sum(r0 * r0 + r1 * r1);
    float y2 = wave_sum(b0 * b0 + b1 * b1);
    float xy = wave_sum(r0 * b0 + r1 * b1);
    float ca = 1.0f + 2.0f * xy + y2;
    float cb = 1.0f - x2;
    float den = fmaxf(1.0f + 2.0f * xy + x2 * y2, MINN);
    float h0 = (ca * r0 + cb * b0) / den;
    float h1 = (ca * r1 + cb * b1) / den;
    // proj
    float hn = fmaxf(sqrtf(wave_sum(h0 * h0 + h1 * h1)), MINN);
    if (hn > MAXN) { float f = MAXN / hn; h0 *= f; h1 *= f; }
    // logmap0
    float hn2 = fmaxf(sqrtf(wave_sum(h0 * h0 + h1 * h1)), MINN);
    float ls = artanh_clip(hn2) / hn2;
    float2 o; o.x = ls * h0; o.y = ls * h1;
    ((float2*)(MX + (size_t)row * D))[lane] = o;
}

// ------- scatter: out[row] += val * xt[col], f32 atomics, 32 threads/edge -------
__global__ __launch_bounds__(256)
void scatter_kernel(const float* __restrict__ XT, const float* __restrict__ adj,
                    const int* __restrict__ erow, const int* __restrict__ ecol,
                    float* __restrict__ OUT, int E)
{
    long long tid = (long long)blockIdx.x * blockDim.x + threadIdx.x;
    int e = (int)(tid >> 5);
    int part = (int)(tid & 31);
    if (e >= E) return;
    int col = ecol[e], row = erow[e];
    float v = adj[e];
    float4 m = ((const float4*)(XT + (size_t)col * D))[part];
    float* dst = OUT + (size_t)row * D + part * 4;
    atomicAdd(dst + 0, v * m.x);
    atomicAdd(dst + 1, v * m.y);
    atomicAdd(dst + 2, v * m.z);
    atomicAdd(dst + 3, v * m.w);
}

// ------- rowC: clamp + expmap0 + proj + logmap0 + relu + clamp + expmap0, in place -------
__global__ __launch_bounds__(256)
void rowC_kernel(float* __restrict__ OUT, int N)
{
    int row = blockIdx.x * 4 + (threadIdx.x >> 6);
    int lane = threadIdx.x & 63;
    if (row >= N) return;
    float2 t = ((float2*)(OUT + (size_t)row * D))[lane];
    t.x = fminf(t.x, MAX_NORM); t.y = fminf(t.y, MAX_NORM);
    float nt = fmaxf(sqrtf(wave_sum(t.x * t.x + t.y * t.y)), MINN);
    float es = tanhf(nt) / nt;
    float h0 = es * t.x, h1 = es * t.y;
    float hn = fmaxf(sqrtf(wave_sum(h0 * h0 + h1 * h1)), MINN);
    if (hn > MAXN) { float f = MAXN / hn; h0 *= f; h1 *= f; }
    float hn2 = fmaxf(sqrtf(wave_sum(h0 * h0 + h1 * h1)), MINN);
    float ls = artanh_clip(hn2) / hn2;
    float u0 = fminf(fmaxf(ls * h0, 0.0f), MAX_NORM);
    float u1 = fminf(fmaxf(ls * h1, 0.0f), MAX_NORM);
    float un = fmaxf(sqrtf(wave_sum(u0 * u0 + u1 * u1)), MINN);
    float os = tanhf(un) / un;
    float2 o; o.x = os * u0; o.y = os * u1;
    ((float2*)(OUT + (size_t)row * D))[lane] = o;
}

extern "C" void kernel_launch(void* const* d_in, const int* in_sizes, int n_in,
                              void* d_out, int out_size, void* d_ws, size_t ws_size,
                              hipStream_t stream)
{
    const float* x    = (const float*)d_in[0];
    const float* adj  = (const float*)d_in[1];
    const float* W    = (const float*)d_in[2];
    const float* bias = (const float*)d_in[3];
    const int*   erow = (const int*)d_in[4];
    const int*   ecol = (const int*)d_in[5];
    float* out = (float*)d_out;
    float* mx  = (float*)d_ws;   // [N*D] fp32: mx, then x_tangent (in place)
    const int N = in_sizes[0] / D;
    const int E = in_sizes[1];

    // d_out doubles as the zeroed scatter accumulator
    hipMemsetAsync(out, 0, (size_t)out_size * sizeof(float), stream);

    gemm_kernel<<<(N + 31) / 32, 256, 0, stream>>>(x, W, mx, N);
    rowA_kernel<<<(N + 3) / 4, 256, 0, stream>>>(x, mx, bias, N);
    long long sthreads = (long long)E * 32;
    scatter_kernel<<<(unsigned)((sthreads + 255) / 256), 256, 0, stream>>>(mx, adj, erow, ecol, out, E);
    rowC_kernel<<<(N + 3) / 4, 256, 0, stream>>>(out, N);
}

// Round 2
// 231.946 us; speedup vs baseline: 6.2146x; 6.2146x over previous
//
#include <hip/hip_runtime.h>

#define D 128
#define MAXN 0.996f            // (1 - BALL_EPS) / sqrt(c), c = 1
#define MINN 1e-15f
#define ARTANH_MAX (1.0f - 1e-7f)
#define MAX_NORM 1e6f

__device__ __forceinline__ float wave_sum(float v) {
#pragma unroll
    for (int o = 32; o > 0; o >>= 1) v += __shfl_xor(v, o, 64);
    return v;
}

__device__ __forceinline__ float artanh_clip(float x) {
    x = fminf(fmaxf(x, -ARTANH_MAX), ARTANH_MAX);
    return 0.5f * logf((1.0f + x) / (1.0f - x));
}

// ---------------- GEMM: mx[i][j] = sum_k x[i][k] * W[j][k] ----------------
__global__ __launch_bounds__(256)
void gemm_kernel(const float* __restrict__ X, const float* __restrict__ W,
                 float* __restrict__ MX, int N)
{
    __shared__ float xs[32][36];    // xs[k][r] (transposed), padded
    __shared__ float wl[32][132];   // wl[k][c], padded
    const int tid = threadIdx.x;
    const int row0 = blockIdx.x * 32;
    const int ct = tid & 31;        // col group: cols ct*4..+3
    const int rt = tid >> 5;        // row group: rows rt*4..+3
    float acc[4][4] = {{0.f}};

    for (int k0 = 0; k0 < D; k0 += 32) {
        {
            int r = tid >> 3;
            int kq = (tid & 7) * 4;
            int rr = row0 + r;
            float4 v = make_float4(0.f, 0.f, 0.f, 0.f);
            if (rr < N) v = *(const float4*)(X + (size_t)rr * D + k0 + kq);
            xs[kq + 0][r] = v.x; xs[kq + 1][r] = v.y;
            xs[kq + 2][r] = v.z; xs[kq + 3][r] = v.w;
        }
        {
            int c = tid >> 1;
            int kh = (tid & 1) * 16;
            const float* wp = W + (size_t)c * D + k0 + kh;
#pragma unroll
            for (int i = 0; i < 16; i += 4) {
                float4 v = *(const float4*)(wp + i);
                wl[kh + i + 0][c] = v.x; wl[kh + i + 1][c] = v.y;
                wl[kh + i + 2][c] = v.z; wl[kh + i + 3][c] = v.w;
            }
        }
        __syncthreads();
#pragma unroll
        for (int k = 0; k < 32; ++k) {
            float4 a = *(const float4*)&xs[k][rt * 4];
            float4 b = *(const float4*)&wl[k][ct * 4];
            acc[0][0] += a.x * b.x; acc[0][1] += a.x * b.y; acc[0][2] += a.x * b.z; acc[0][3] += a.x * b.w;
            acc[1][0] += a.y * b.x; acc[1][1] += a.y * b.y; acc[1][2] += a.y * b.z; acc[1][3] += a.y * b.w;
            acc[2][0] += a.z * b.x; acc[2][1] += a.z * b.y; acc[2][2] += a.z * b.z; acc[2][3] += a.z * b.w;
            acc[3][0] += a.w * b.x; acc[3][1] += a.w * b.y; acc[3][2] += a.w * b.z; acc[3][3] += a.w * b.w;
        }
        __syncthreads();
    }
#pragma unroll
    for (int i = 0; i < 4; ++i) {
        int rr = row0 + rt * 4 + i;
        if (rr < N) {
            float4 o = make_float4(acc[i][0], acc[i][1], acc[i][2], acc[i][3]);
            *(float4*)(MX + (size_t)rr * D + ct * 4) = o;
        }
    }
}

// ------- rowA: mobius_matvec tail + proj + bias mobius_add + proj + logmap0 -------
__global__ __launch_bounds__(256)
void rowA_kernel(const float* __restrict__ X, float* __restrict__ MX,
                 const float* __restrict__ bias, int N)
{
    int row = blockIdx.x * 4 + (threadIdx.x >> 6);
    int lane = threadIdx.x & 63;
    if (row >= N) return;
    const float2 xv = ((const float2*)(X + (size_t)row * D))[lane];
    float2 mv = ((float2*)(MX + (size_t)row * D))[lane];
    const float2 bv = ((const float2*)bias)[lane];

    float xn  = fmaxf(sqrtf(wave_sum(xv.x * xv.x + xv.y * xv.y)), MINN);
    float mxn = fmaxf(sqrtf(wave_sum(mv.x * mv.x + mv.y * mv.y)), MINN);
    float sc = tanhf(mxn / xn * artanh_clip(xn)) / mxn;
    float r0 = sc * mv.x, r1 = sc * mv.y;
    if (__all(mv.x == 0.0f && mv.y == 0.0f)) { r0 = 0.0f; r1 = 0.0f; }
    float rn = fmaxf(sqrtf(wave_sum(r0 * r0 + r1 * r1)), MINN);
    if (rn > MAXN) { float f = MAXN / rn; r0 *= f; r1 *= f; }
    float bn = fmaxf(sqrtf(wave_sum(bv.x * bv.x + bv.y * bv.y)), MINN);
    float bs = tanhf(bn) / bn;
    float b0 = bs * bv.x, b1 = bs * bv.y;
    float hbn = fmaxf(sqrtf(wave_sum(b0 * b0 + b1 * b1)), MINN);
    if (hbn > MAXN) { float f = MAXN / hbn; b0 *= f; b1 *= f; }
    float x2 = wave_sum(r0 * r0 + r1 * r1);
    float y2 = wave_sum(b0 * b0 + b1 * b1);
    float xy = wave_sum(r0 * b0 + r1 * b1);
    float ca = 1.0f + 2.0f * xy + y2;
    float cb = 1.0f - x2;
    float den = fmaxf(1.0f + 2.0f * xy + x2 * y2, MINN);
    float h0 = (ca * r0 + cb * b0) / den;
    float h1 = (ca * r1 + cb * b1) / den;
    float hn = fmaxf(sqrtf(wave_sum(h0 * h0 + h1 * h1)), MINN);
    if (hn > MAXN) { float f = MAXN / hn; h0 *= f; h1 *= f; }
    float hn2 = fmaxf(sqrtf(wave_sum(h0 * h0 + h1 * h1)), MINN);
    float ls = artanh_clip(hn2) / hn2;
    float2 o; o.x = ls * h0; o.y = ls * h1;
    ((float2*)(MX + (size_t)row * D))[lane] = o;
}

// ---------------- CSR build ----------------
__global__ __launch_bounds__(256)
void hist_kernel(const int* __restrict__ erow, int* __restrict__ cnt, int E)
{
    int e = blockIdx.x * 256 + threadIdx.x;
    if (e < E) atomicAdd(&cnt[erow[e]], 1);
}

// block-level partial exclusive scan: 1024 elems/block (256 thr x 4)
__global__ __launch_bounds__(256)
void scan1_kernel(const int* __restrict__ cnt, int* __restrict__ offs,
                  int* __restrict__ bsum, int N)
{
    __shared__ int wsum[4];
    int t = threadIdx.x;
    int base = blockIdx.x * 1024 + t * 4;
    int v[4];
#pragma unroll
    for (int j = 0; j < 4; ++j) v[j] = (base + j < N) ? cnt[base + j] : 0;
    int tt = v[0] + v[1] + v[2] + v[3];
    int incl = tt;
#pragma unroll
    for (int o = 1; o < 64; o <<= 1) {
        int n = __shfl_up(incl, o, 64);
        if ((t & 63) >= o) incl += n;
    }
    if ((t & 63) == 63) wsum[t >> 6] = incl;
    __syncthreads();
    int wbase = 0;
    for (int w = 0; w < (t >> 6); ++w) wbase += wsum[w];
    int ex = wbase + incl - tt;
#pragma unroll
    for (int j = 0; j < 4; ++j) {
        if (base + j < N) offs[base + j] = ex;
        ex += v[j];
    }
    if (t == 255) bsum[blockIdx.x] = wbase + incl;
}

// scan the <=64 block sums in one wave (exclusive)
__global__ __launch_bounds__(64)
void scan2_kernel(int* __restrict__ bsum, int nb)
{
    int l = threadIdx.x;
    int v = (l < nb) ? bsum[l] : 0;
    int incl = v;
#pragma unroll
    for (int o = 1; o < 64; o <<= 1) {
        int n = __shfl_up(incl, o, 64);
        if (l >= o) incl += n;
    }
    if (l < nb) bsum[l] = incl - v;
}

__global__ __launch_bounds__(256)
void scan3_kernel(int* __restrict__ offs, const int* __restrict__ bsum, int N)
{
    int i = blockIdx.x * 256 + threadIdx.x;
    if (i < N) offs[i] += bsum[i >> 10];
}

__global__ __launch_bounds__(256)
void fill_kernel(const int* __restrict__ erow, const int* __restrict__ ecol,
                 const float* __restrict__ adj, const int* __restrict__ offs,
                 int* __restrict__ cur, int* __restrict__ bcol,
                 float* __restrict__ bval, int E)
{
    int e = blockIdx.x * 256 + threadIdx.x;
    if (e >= E) return;
    int r = erow[e];
    int p = offs[r] + atomicAdd(&cur[r], 1);
    bcol[p] = ecol[e];
    bval[p] = adj[e];
}

// ------- gather + fused HypAct tail: one wave per row, register accumulation -------
__global__ __launch_bounds__(256)
void gather_kernel(const float* __restrict__ XT, const int* __restrict__ bcol,
                   const float* __restrict__ bval, const int* __restrict__ offs,
                   const int* __restrict__ cnt, float* __restrict__ OUT, int N)
{
    int row = blockIdx.x * 4 + (threadIdx.x >> 6);
    int lane = threadIdx.x & 63;
    if (row >= N) return;
    int start = offs[row], deg = cnt[row];
    float a0 = 0.f, a1 = 0.f, b0 = 0.f, b1 = 0.f;
    int i = 0;
    for (; i + 1 < deg; i += 2) {
        int c0 = bcol[start + i], c1 = bcol[start + i + 1];
        float v0 = bval[start + i], v1 = bval[start + i + 1];
        float2 m0 = ((const float2*)(XT + (size_t)c0 * D))[lane];
        float2 m1 = ((const float2*)(XT + (size_t)c1 * D))[lane];
        a0 += v0 * m0.x; a1 += v0 * m0.y;
        b0 += v1 * m1.x; b1 += v1 * m1.y;
    }
    if (i < deg) {
        int c = bcol[start + i];
        float v = bval[start + i];
        float2 m = ((const float2*)(XT + (size_t)c * D))[lane];
        a0 += v * m.x; a1 += v * m.y;
    }
    float tx = fminf(a0 + b0, MAX_NORM);
    float ty = fminf(a1 + b1, MAX_NORM);
    // expmap0 + proj
    float nt = fmaxf(sqrtf(wave_sum(tx * tx + ty * ty)), MINN);
    float es = tanhf(nt) / nt;
    float h0 = es * tx, h1 = es * ty;
    float hn = fmaxf(sqrtf(wave_sum(h0 * h0 + h1 * h1)), MINN);
    if (hn > MAXN) { float f = MAXN / hn; h0 *= f; h1 *= f; }
    // logmap0 + relu + clamp
    float hn2 = fmaxf(sqrtf(wave_sum(h0 * h0 + h1 * h1)), MINN);
    float ls = artanh_clip(hn2) / hn2;
    float u0 = fminf(fmaxf(ls * h0, 0.0f), MAX_NORM);
    float u1 = fminf(fmaxf(ls * h1, 0.0f), MAX_NORM);
    // expmap0
    float un = fmaxf(sqrtf(wave_sum(u0 * u0 + u1 * u1)), MINN);
    float os = tanhf(un) / un;
    float2 o; o.x = os * u0; o.y = os * u1;
    ((float2*)(OUT + (size_t)row * D))[lane] = o;
}

// ---------------- fallback atomic path (if ws too small) ----------------
__global__ __launch_bounds__(256)
void scatter_kernel(const float* __restrict__ XT, const float* __restrict__ adj,
                    const int* __restrict__ erow, const int* __restrict__ ecol,
                    float* __restrict__ OUT, int E)
{
    long long tid = (long long)blockIdx.x * blockDim.x + threadIdx.x;
    int e = (int)(tid >> 5);
    int part = (int)(tid & 31);
    if (e >= E) return;
    int col = ecol[e], row = erow[e];
    float v = adj[e];
    float4 m = ((const float4*)(XT + (size_t)col * D))[part];
    float* dst = OUT + (size_t)row * D + part * 4;
    atomicAdd(dst + 0, v * m.x);
    atomicAdd(dst + 1, v * m.y);
    atomicAdd(dst + 2, v * m.z);
    atomicAdd(dst + 3, v * m.w);
}

__global__ __launch_bounds__(256)
void rowC_kernel(float* __restrict__ OUT, int N)
{
    int row = blockIdx.x * 4 + (threadIdx.x >> 6);
    int lane = threadIdx.x & 63;
    if (row >= N) return;
    float2 t = ((float2*)(OUT + (size_t)row * D))[lane];
    t.x = fminf(t.x, MAX_NORM); t.y = fminf(t.y, MAX_NORM);
    float nt = fmaxf(sqrtf(wave_sum(t.x * t.x + t.y * t.y)), MINN);
    float es = tanhf(nt) / nt;
    float h0 = es * t.x, h1 = es * t.y;
    float hn = fmaxf(sqrtf(wave_sum(h0 * h0 + h1 * h1)), MINN);
    if (hn > MAXN) { float f = MAXN / hn; h0 *= f; h1 *= f; }
    float hn2 = fmaxf(sqrtf(wave_sum(h0 * h0 + h1 * h1)), MINN);
    float ls = artanh_clip(hn2) / hn2;
    float u0 = fminf(fmaxf(ls * h0, 0.0f), MAX_NORM);
    float u1 = fminf(fmaxf(ls * h1, 0.0f), MAX_NORM);
    float un = fmaxf(sqrtf(wave_sum(u0 * u0 + u1 * u1)), MINN);
    float os = tanhf(un) / un;
    float2 o; o.x = os * u0; o.y = os * u1;
    ((float2*)(OUT + (size_t)row * D))[lane] = o;
}

extern "C" void kernel_launch(void* const* d_in, const int* in_sizes, int n_in,
                              void* d_out, int out_size, void* d_ws, size_t ws_size,
                              hipStream_t stream)
{
    const float* x    = (const float*)d_in[0];
    const float* adj  = (const float*)d_in[1];
    const float* W    = (const float*)d_in[2];
    const float* bias = (const float*)d_in[3];
    const int*   erow = (const int*)d_in[4];
    const int*   ecol = (const int*)d_in[5];
    float* out = (float*)d_out;
    const int N = in_sizes[0] / D;
    const int E = in_sizes[1];

    // workspace layout (256B aligned segments)
    char* p = (char*)d_ws;
    size_t off = 0;
    auto alloc = [&](size_t bytes) {
        char* r = p + off;
        off = (off + bytes + 255) & ~(size_t)255;
        return r;
    };
    float* xt   = (float*)alloc((size_t)N * D * sizeof(float));
    int*   cnt  = (int*)  alloc((size_t)N * sizeof(int));
    int*   cur  = (int*)  alloc((size_t)N * sizeof(int));
    int*   offs = (int*)  alloc((size_t)N * sizeof(int));
    int*   bsum = (int*)  alloc(256 * sizeof(int));
    int*   bcol = (int*)  alloc((size_t)E * sizeof(int));
    float* bval = (float*)alloc((size_t)E * sizeof(float));
    bool csr_ok = (off <= ws_size);

    gemm_kernel<<<(N + 31) / 32, 256, 0, stream>>>(x, W, xt, N);
    rowA_kernel<<<(N + 3) / 4, 256, 0, stream>>>(x, xt, bias, N);

    if (csr_ok) {
        hipMemsetAsync(cnt, 0, (size_t)N * sizeof(int), stream);
        hipMemsetAsync(cur, 0, (size_t)N * sizeof(int), stream);
        hist_kernel<<<(E + 255) / 256, 256, 0, stream>>>(erow, cnt, E);
        int nb = (N + 1023) / 1024;   // 49 for N=50000, must be <= 64
        scan1_kernel<<<nb, 256, 0, stream>>>(cnt, offs, bsum, N);
        scan2_kernel<<<1, 64, 0, stream>>>(bsum, nb);
        scan3_kernel<<<(N + 255) / 256, 256, 0, stream>>>(offs, bsum, N);
        fill_kernel<<<(E + 255) / 256, 256, 0, stream>>>(erow, ecol, adj, offs, cur, bcol, bval, E);
        gather_kernel<<<(N + 3) / 4, 256, 0, stream>>>(xt, bcol, bval, offs, cnt, out, N);
    } else {
        hipMemsetAsync(out, 0, (size_t)out_size * sizeof(float), stream);
        long long sthreads = (long long)E * 32;
        scatter_kernel<<<(unsigned)((sthreads + 255) / 256), 256, 0, stream>>>(xt, adj, erow, ecol, out, E);
        rowC_kernel<<<(N + 3) / 4, 256, 0, stream>>>(out, N);
    }
}

// Round 3
// 225.151 us; speedup vs baseline: 6.4021x; 1.0302x over previous
//
#include <hip/hip_runtime.h>

#define D 128
#define MAXN 0.996f            // (1 - BALL_EPS) / sqrt(c), c = 1
#define MINN 1e-15f
#define ARTANH_MAX (1.0f - 1e-7f)
#define MAX_NORM 1e6f

__device__ __forceinline__ float wave_sum(float v) {
#pragma unroll
    for (int o = 32; o > 0; o >>= 1) v += __shfl_xor(v, o, 64);
    return v;
}

__device__ __forceinline__ float artanh_clip(float x) {
    x = fminf(fmaxf(x, -ARTANH_MAX), ARTANH_MAX);
    return 0.5f * logf((1.0f + x) / (1.0f - x));
}

// ---- GEMM: mx[i][j] = sum_k x[i][k] * W[j][k]; also emits xnorm2[i] = ||x_i||^2 ----
__global__ __launch_bounds__(256)
void gemm_kernel(const float* __restrict__ X, const float* __restrict__ W,
                 float* __restrict__ MX, float* __restrict__ XN2, int N)
{
    __shared__ float xs[32][36];    // xs[k][r] (transposed), padded
    __shared__ float wl[32][132];   // wl[k][c], padded
    const int tid = threadIdx.x;
    const int row0 = blockIdx.x * 32;
    const int ct = tid & 31;        // col group: cols ct*4..+3
    const int rt = tid >> 5;        // row group: rows rt*4..+3
    float acc[4][4] = {{0.f}};
    float xsq = 0.f;                // partial ||x_row||^2 for row tid>>3

    for (int k0 = 0; k0 < D; k0 += 32) {
        {
            int r = tid >> 3;
            int kq = (tid & 7) * 4;
            int rr = row0 + r;
            float4 v = make_float4(0.f, 0.f, 0.f, 0.f);
            if (rr < N) v = *(const float4*)(X + (size_t)rr * D + k0 + kq);
            xsq += v.x * v.x + v.y * v.y + v.z * v.z + v.w * v.w;
            xs[kq + 0][r] = v.x; xs[kq + 1][r] = v.y;
            xs[kq + 2][r] = v.z; xs[kq + 3][r] = v.w;
        }
        {
            int c = tid >> 1;
            int kh = (tid & 1) * 16;
            const float* wp = W + (size_t)c * D + k0 + kh;
#pragma unroll
            for (int i = 0; i < 16; i += 4) {
                float4 v = *(const float4*)(wp + i);
                wl[kh + i + 0][c] = v.x; wl[kh + i + 1][c] = v.y;
                wl[kh + i + 2][c] = v.z; wl[kh + i + 3][c] = v.w;
            }
        }
        __syncthreads();
#pragma unroll
        for (int k = 0; k < 32; ++k) {
            float4 a = *(const float4*)&xs[k][rt * 4];
            float4 b = *(const float4*)&wl[k][ct * 4];
            acc[0][0] += a.x * b.x; acc[0][1] += a.x * b.y; acc[0][2] += a.x * b.z; acc[0][3] += a.x * b.w;
            acc[1][0] += a.y * b.x; acc[1][1] += a.y * b.y; acc[1][2] += a.y * b.z; acc[1][3] += a.y * b.w;
            acc[2][0] += a.z * b.x; acc[2][1] += a.z * b.y; acc[2][2] += a.z * b.z; acc[2][3] += a.z * b.w;
            acc[3][0] += a.w * b.x; acc[3][1] += a.w * b.y; acc[3][2] += a.w * b.z; acc[3][3] += a.w * b.w;
        }
        __syncthreads();
    }
    // reduce xsq over the 8 staging lanes of each row (aligned 8-lane groups)
    xsq += __shfl_xor(xsq, 1, 64);
    xsq += __shfl_xor(xsq, 2, 64);
    xsq += __shfl_xor(xsq, 4, 64);
    if ((tid & 7) == 0) {
        int rr = row0 + (tid >> 3);
        if (rr < N) XN2[rr] = xsq;
    }
#pragma unroll
    for (int i = 0; i < 4; ++i) {
        int rr = row0 + rt * 4 + i;
        if (rr < N) {
            float4 o = make_float4(acc[i][0], acc[i][1], acc[i][2], acc[i][3]);
            *(float4*)(MX + (size_t)rr * D + ct * 4) = o;
        }
    }
}

// ------- rowA: mobius_matvec tail + proj + bias mobius_add + proj + logmap0 -------
__global__ __launch_bounds__(256)
void rowA_kernel(float* __restrict__ MX, const float* __restrict__ XN2,
                 const float* __restrict__ bias, int N)
{
    int row = blockIdx.x * 4 + (threadIdx.x >> 6);
    int lane = threadIdx.x & 63;
    if (row >= N) return;
    float2 mv = ((float2*)(MX + (size_t)row * D))[lane];
    const float2 bv = ((const float2*)bias)[lane];

    float xn  = fmaxf(sqrtf(XN2[row]), MINN);
    float mxn = fmaxf(sqrtf(wave_sum(mv.x * mv.x + mv.y * mv.y)), MINN);
    float sc = tanhf(mxn / xn * artanh_clip(xn)) / mxn;
    float r0 = sc * mv.x, r1 = sc * mv.y;
    if (__all(mv.x == 0.0f && mv.y == 0.0f)) { r0 = 0.0f; r1 = 0.0f; }
    float rn = fmaxf(sqrtf(wave_sum(r0 * r0 + r1 * r1)), MINN);
    if (rn > MAXN) { float f = MAXN / rn; r0 *= f; r1 *= f; }
    float bn = fmaxf(sqrtf(wave_sum(bv.x * bv.x + bv.y * bv.y)), MINN);
    float bs = tanhf(bn) / bn;
    float b0 = bs * bv.x, b1 = bs * bv.y;
    float hbn = fmaxf(sqrtf(wave_sum(b0 * b0 + b1 * b1)), MINN);
    if (hbn > MAXN) { float f = MAXN / hbn; b0 *= f; b1 *= f; }
    float x2 = wave_sum(r0 * r0 + r1 * r1);
    float y2 = wave_sum(b0 * b0 + b1 * b1);
    float xy = wave_sum(r0 * b0 + r1 * b1);
    float ca = 1.0f + 2.0f * xy + y2;
    float cb = 1.0f - x2;
    float den = fmaxf(1.0f + 2.0f * xy + x2 * y2, MINN);
    float h0 = (ca * r0 + cb * b0) / den;
    float h1 = (ca * r1 + cb * b1) / den;
    float hn = fmaxf(sqrtf(wave_sum(h0 * h0 + h1 * h1)), MINN);
    if (hn > MAXN) { float f = MAXN / hn; h0 *= f; h1 *= f; }
    float hn2 = fmaxf(sqrtf(wave_sum(h0 * h0 + h1 * h1)), MINN);
    float ls = artanh_clip(hn2) / hn2;
    float2 o; o.x = ls * h0; o.y = ls * h1;
    ((float2*)(MX + (size_t)row * D))[lane] = o;
}

// ---------------- CSR build ----------------
__global__ __launch_bounds__(256)
void hist_kernel(const int* __restrict__ erow, int* __restrict__ cnt, int E)
{
    int e = blockIdx.x * 256 + threadIdx.x;
    if (e < E) atomicAdd(&cnt[erow[e]], 1);
}

// block-level partial exclusive scan: 1024 elems/block (256 thr x 4)
__global__ __launch_bounds__(256)
void scan1_kernel(const int* __restrict__ cnt, int* __restrict__ offs,
                  int* __restrict__ bsum, int N)
{
    __shared__ int wsum[4];
    int t = threadIdx.x;
    int base = blockIdx.x * 1024 + t * 4;
    int v[4];
#pragma unroll
    for (int j = 0; j < 4; ++j) v[j] = (base + j < N) ? cnt[base + j] : 0;
    int tt = v[0] + v[1] + v[2] + v[3];
    int incl = tt;
#pragma unroll
    for (int o = 1; o < 64; o <<= 1) {
        int n = __shfl_up(incl, o, 64);
        if ((t & 63) >= o) incl += n;
    }
    if ((t & 63) == 63) wsum[t >> 6] = incl;
    __syncthreads();
    int wbase = 0;
    for (int w = 0; w < (t >> 6); ++w) wbase += wsum[w];
    int ex = wbase + incl - tt;
#pragma unroll
    for (int j = 0; j < 4; ++j) {
        if (base + j < N) offs[base + j] = ex;
        ex += v[j];
    }
    if (t == 255) bsum[blockIdx.x] = wbase + incl;
}

// scan the <=64 block sums in one wave (exclusive)
__global__ __launch_bounds__(64)
void scan2_kernel(int* __restrict__ bsum, int nb)
{
    int l = threadIdx.x;
    int v = (l < nb) ? bsum[l] : 0;
    int incl = v;
#pragma unroll
    for (int o = 1; o < 64; o <<= 1) {
        int n = __shfl_up(incl, o, 64);
        if (l >= o) incl += n;
    }
    if (l < nb) bsum[l] = incl - v;
}

// fixup partial scan AND seed cur[] with the final offsets
__global__ __launch_bounds__(256)
void seed_kernel(int* __restrict__ offs, const int* __restrict__ bsum,
                 int* __restrict__ cur, int N)
{
    int i = blockIdx.x * 256 + threadIdx.x;
    if (i < N) {
        int v = offs[i] + bsum[i >> 10];
        offs[i] = v;
        cur[i] = v;
    }
}

__global__ __launch_bounds__(256)
void fill_kernel(const int* __restrict__ erow, const int* __restrict__ ecol,
                 const float* __restrict__ adj, int* __restrict__ cur,
                 int2* __restrict__ bpack, int E)
{
    int e = blockIdx.x * 256 + threadIdx.x;
    if (e >= E) return;
    int p = atomicAdd(&cur[erow[e]], 1);
    bpack[p] = make_int2(ecol[e], __float_as_int(adj[e]));
}

// ------- gather + fused HypAct tail: one wave per row, register accumulation -------
__global__ __launch_bounds__(256)
void gather_kernel(const float* __restrict__ XT, const int2* __restrict__ bpack,
                   const int* __restrict__ offs, const int* __restrict__ cnt,
                   float* __restrict__ OUT, int N)
{
    int row = blockIdx.x * 4 + (threadIdx.x >> 6);
    int lane = threadIdx.x & 63;
    if (row >= N) return;
    int start = offs[row], deg = cnt[row];
    float a0 = 0.f, a1 = 0.f, b0 = 0.f, b1 = 0.f;
    int i = 0;
    for (; i + 1 < deg; i += 2) {
        int2 e0 = bpack[start + i];
        int2 e1 = bpack[start + i + 1];
        float v0 = __int_as_float(e0.y), v1 = __int_as_float(e1.y);
        float2 m0 = ((const float2*)(XT + (size_t)e0.x * D))[lane];
        float2 m1 = ((const float2*)(XT + (size_t)e1.x * D))[lane];
        a0 += v0 * m0.x; a1 += v0 * m0.y;
        b0 += v1 * m1.x; b1 += v1 * m1.y;
    }
    if (i < deg) {
        int2 e0 = bpack[start + i];
        float v = __int_as_float(e0.y);
        float2 m = ((const float2*)(XT + (size_t)e0.x * D))[lane];
        a0 += v * m.x; a1 += v * m.y;
    }
    float tx = fminf(a0 + b0, MAX_NORM);
    float ty = fminf(a1 + b1, MAX_NORM);
    // expmap0 + proj
    float nt = fmaxf(sqrtf(wave_sum(tx * tx + ty * ty)), MINN);
    float es = tanhf(nt) / nt;
    float h0 = es * tx, h1 = es * ty;
    float hn = fmaxf(sqrtf(wave_sum(h0 * h0 + h1 * h1)), MINN);
    if (hn > MAXN) { float f = MAXN / hn; h0 *= f; h1 *= f; }
    // logmap0 + relu + clamp
    float hn2 = fmaxf(sqrtf(wave_sum(h0 * h0 + h1 * h1)), MINN);
    float ls = artanh_clip(hn2) / hn2;
    float u0 = fminf(fmaxf(ls * h0, 0.0f), MAX_NORM);
    float u1 = fminf(fmaxf(ls * h1, 0.0f), MAX_NORM);
    // expmap0
    float un = fmaxf(sqrtf(wave_sum(u0 * u0 + u1 * u1)), MINN);
    float os = tanhf(un) / un;
    float2 o; o.x = os * u0; o.y = os * u1;
    ((float2*)(OUT + (size_t)row * D))[lane] = o;
}

// ---------------- fallback atomic path (if ws too small) ----------------
__global__ __launch_bounds__(256)
void scatter_kernel(const float* __restrict__ XT, const float* __restrict__ adj,
                    const int* __restrict__ erow, const int* __restrict__ ecol,
                    float* __restrict__ OUT, int E)
{
    long long tid = (long long)blockIdx.x * blockDim.x + threadIdx.x;
    int e = (int)(tid >> 5);
    int part = (int)(tid & 31);
    if (e >= E) return;
    int col = ecol[e], row = erow[e];
    float v = adj[e];
    float4 m = ((const float4*)(XT + (size_t)col * D))[part];
    float* dst = OUT + (size_t)row * D + part * 4;
    atomicAdd(dst + 0, v * m.x);
    atomicAdd(dst + 1, v * m.y);
    atomicAdd(dst + 2, v * m.z);
    atomicAdd(dst + 3, v * m.w);
}

__global__ __launch_bounds__(256)
void rowC_kernel(float* __restrict__ OUT, int N)
{
    int row = blockIdx.x * 4 + (threadIdx.x >> 6);
    int lane = threadIdx.x & 63;
    if (row >= N) return;
    float2 t = ((float2*)(OUT + (size_t)row * D))[lane];
    t.x = fminf(t.x, MAX_NORM); t.y = fminf(t.y, MAX_NORM);
    float nt = fmaxf(sqrtf(wave_sum(t.x * t.x + t.y * t.y)), MINN);
    float es = tanhf(nt) / nt;
    float h0 = es * t.x, h1 = es * t.y;
    float hn = fmaxf(sqrtf(wave_sum(h0 * h0 + h1 * h1)), MINN);
    if (hn > MAXN) { float f = MAXN / hn; h0 *= f; h1 *= f; }
    float hn2 = fmaxf(sqrtf(wave_sum(h0 * h0 + h1 * h1)), MINN);
    float ls = artanh_clip(hn2) / hn2;
    float u0 = fminf(fmaxf(ls * h0, 0.0f), MAX_NORM);
    float u1 = fminf(fmaxf(ls * h1, 0.0f), MAX_NORM);
    float un = fmaxf(sqrtf(wave_sum(u0 * u0 + u1 * u1)), MINN);
    float os = tanhf(un) / un;
    float2 o; o.x = os * u0; o.y = os * u1;
    ((float2*)(OUT + (size_t)row * D))[lane] = o;
}

extern "C" void kernel_launch(void* const* d_in, const int* in_sizes, int n_in,
                              void* d_out, int out_size, void* d_ws, size_t ws_size,
                              hipStream_t stream)
{
    const float* x    = (const float*)d_in[0];
    const float* adj  = (const float*)d_in[1];
    const float* W    = (const float*)d_in[2];
    const float* bias = (const float*)d_in[3];
    const int*   erow = (const int*)d_in[4];
    const int*   ecol = (const int*)d_in[5];
    float* out = (float*)d_out;
    const int N = in_sizes[0] / D;
    const int E = in_sizes[1];

    // workspace layout (256B aligned segments)
    char* p = (char*)d_ws;
    size_t off = 0;
    auto alloc = [&](size_t bytes) {
        char* r = p + off;
        off = (off + bytes + 255) & ~(size_t)255;
        return r;
    };
    float* xt   = (float*)alloc((size_t)N * D * sizeof(float));
    float* xn2  = (float*)alloc((size_t)N * sizeof(float));
    int*   cnt  = (int*)  alloc((size_t)N * sizeof(int));
    int*   cur  = (int*)  alloc((size_t)N * sizeof(int));
    int*   offs = (int*)  alloc((size_t)N * sizeof(int));
    int*   bsum = (int*)  alloc(256 * sizeof(int));
    int2*  bpack= (int2*) alloc((size_t)E * sizeof(int2));
    bool csr_ok = (off <= ws_size);

    gemm_kernel<<<(N + 31) / 32, 256, 0, stream>>>(x, W, xt, xn2, N);
    rowA_kernel<<<(N + 3) / 4, 256, 0, stream>>>(xt, xn2, bias, N);

    if (csr_ok) {
        hipMemsetAsync(cnt, 0, (size_t)N * sizeof(int), stream);
        hist_kernel<<<(E + 255) / 256, 256, 0, stream>>>(erow, cnt, E);
        int nb = (N + 1023) / 1024;   // 49 for N=50000, must be <= 64
        scan1_kernel<<<nb, 256, 0, stream>>>(cnt, offs, bsum, N);
        scan2_kernel<<<1, 64, 0, stream>>>(bsum, nb);
        seed_kernel<<<(N + 255) / 256, 256, 0, stream>>>(offs, bsum, cur, N);
        fill_kernel<<<(E + 255) / 256, 256, 0, stream>>>(erow, ecol, adj, cur, bpack, E);
        gather_kernel<<<(N + 3) / 4, 256, 0, stream>>>(xt, bpack, offs, cnt, out, N);
    } else {
        hipMemsetAsync(out, 0, (size_t)out_size * sizeof(float), stream);
        long long sthreads = (long long)E * 32;
        scatter_kernel<<<(unsigned)((sthreads + 255) / 256), 256, 0, stream>>>(xt, adj, erow, ecol, out, E);
        rowC_kernel<<<(N + 3) / 4, 256, 0, stream>>>(out, N);
    }
}

// Round 4
// 162.643 us; speedup vs baseline: 8.8626x; 1.3843x over previous
//
#include <hip/hip_runtime.h>

#define D 128
#define MAXN 0.996f            // (1 - BALL_EPS) / sqrt(c), c = 1
#define MINN 1e-15f
#define ARTANH_MAX (1.0f - 1e-7f)
#define MAX_NORM 1e6f

typedef unsigned int uint;
typedef unsigned short ushort;

__device__ __forceinline__ float wave_sum(float v) {
#pragma unroll
    for (int o = 32; o > 0; o >>= 1) v += __shfl_xor(v, o, 64);
    return v;
}

// reduce across an aligned 32-lane group (stays inside each half of a wave64)
__device__ __forceinline__ float half_sum(float v) {
#pragma unroll
    for (int o = 16; o > 0; o >>= 1) v += __shfl_xor(v, o, 64);
    return v;
}

__device__ __forceinline__ float artanh_clip(float x) {
    x = fminf(fmaxf(x, -ARTANH_MAX), ARTANH_MAX);
    return 0.5f * logf((1.0f + x) / (1.0f - x));
}

__device__ __forceinline__ ushort f2bf(float f) {   // RNE, finite inputs
    uint u = __float_as_uint(f);
    return (ushort)((u + 0x7fffu + ((u >> 16) & 1u)) >> 16);
}

// ---- GEMM + fused HypLinear: xt[i][:] = A_i * (x_i @ W^T) + B_i * b_hyp, bf16 out ----
__global__ __launch_bounds__(256)
void gemm_kernel(const float* __restrict__ X, const float* __restrict__ W,
                 const float* __restrict__ bias, ushort* __restrict__ XT, int N)
{
    __shared__ float xs[32][36];    // xs[k][r] (transposed), padded
    __shared__ float wl[32][132];   // wl[k][c], padded
    __shared__ float xn2s[32];      // ||x_row||^2
    const int tid = threadIdx.x;
    const int row0 = blockIdx.x * 32;
    const int ct = tid & 31;        // col group: cols ct*4..+3
    const int rt = tid >> 5;        // row group: rows rt*4..+3
    float acc[4][4] = {{0.f}};
    float xsq = 0.f;                // partial ||x_row||^2 for staging row tid>>3

    for (int k0 = 0; k0 < D; k0 += 32) {
        {
            int r = tid >> 3;
            int kq = (tid & 7) * 4;
            int rr = row0 + r;
            float4 v = make_float4(0.f, 0.f, 0.f, 0.f);
            if (rr < N) v = *(const float4*)(X + (size_t)rr * D + k0 + kq);
            xsq += v.x * v.x + v.y * v.y + v.z * v.z + v.w * v.w;
            xs[kq + 0][r] = v.x; xs[kq + 1][r] = v.y;
            xs[kq + 2][r] = v.z; xs[kq + 3][r] = v.w;
        }
        {
            int c = tid >> 1;
            int kh = (tid & 1) * 16;
            const float* wp = W + (size_t)c * D + k0 + kh;
#pragma unroll
            for (int i = 0; i < 16; i += 4) {
                float4 v = *(const float4*)(wp + i);
                wl[kh + i + 0][c] = v.x; wl[kh + i + 1][c] = v.y;
                wl[kh + i + 2][c] = v.z; wl[kh + i + 3][c] = v.w;
            }
        }
        __syncthreads();
#pragma unroll
        for (int k = 0; k < 32; ++k) {
            float4 a = *(const float4*)&xs[k][rt * 4];
            float4 b = *(const float4*)&wl[k][ct * 4];
            acc[0][0] += a.x * b.x; acc[0][1] += a.x * b.y; acc[0][2] += a.x * b.z; acc[0][3] += a.x * b.w;
            acc[1][0] += a.y * b.x; acc[1][1] += a.y * b.y; acc[1][2] += a.y * b.z; acc[1][3] += a.y * b.w;
            acc[2][0] += a.z * b.x; acc[2][1] += a.z * b.y; acc[2][2] += a.z * b.z; acc[2][3] += a.z * b.w;
            acc[3][0] += a.w * b.x; acc[3][1] += a.w * b.y; acc[3][2] += a.w * b.z; acc[3][3] += a.w * b.w;
        }
        __syncthreads();
    }
    // ||x_row||^2: reduce over the 8 staging lanes of each row, park in LDS
    xsq += __shfl_xor(xsq, 1, 64);
    xsq += __shfl_xor(xsq, 2, 64);
    xsq += __shfl_xor(xsq, 4, 64);
    if ((tid & 7) == 0) xn2s[tid >> 3] = xsq;

    // hyp bias: b = proj(expmap0(bias)); per thread holds cols ct*4..+3
    float4 bv = *(const float4*)(bias + ct * 4);
    float bsq = half_sum(bv.x * bv.x + bv.y * bv.y + bv.z * bv.z + bv.w * bv.w);
    float bn = fmaxf(sqrtf(bsq), MINN);
    float bt = tanhf(bn);                       // ||expmap0(bias)||
    float bps = (bt > MAXN) ? MAXN / fmaxf(bt, MINN) : 1.0f;
    float bsc = bt / bn * bps;
    float b[4] = { bsc * bv.x, bsc * bv.y, bsc * bv.z, bsc * bv.w };
    float bhn = fminf(fmaxf(bt, MINN), MAXN);   // ||b|| after proj
    float y2 = bhn * bhn;
    __syncthreads();                            // xn2s ready

#pragma unroll
    for (int i = 0; i < 4; ++i) {
        int lr = rt * 4 + i;                    // local row 0..31
        float mxn2 = acc[i][0]*acc[i][0] + acc[i][1]*acc[i][1] + acc[i][2]*acc[i][2] + acc[i][3]*acc[i][3];
        float mxb  = acc[i][0]*b[0] + acc[i][1]*b[1] + acc[i][2]*b[2] + acc[i][3]*b[3];
        mxn2 = half_sum(mxn2);
        mxb  = half_sum(mxb);
        // mobius_matvec tail + proj
        float xn  = fmaxf(sqrtf(xn2s[lr]), MINN);
        float mxn = fmaxf(sqrtf(mxn2), MINN);
        float t1  = tanhf(mxn / xn * artanh_clip(xn));   // ||res||
        float s1  = t1 / mxn;                            // res = s1*mx
        float ps1 = (t1 > MAXN) ? MAXN / fmaxf(t1, MINN) : 1.0f;
        float s1p = s1 * ps1;
        float rn  = fminf(fmaxf(t1, MINN), MAXN);
        // mobius_add(res, b):  h = alpha*mx + beta*b
        float x2 = rn * rn;
        float xy = s1p * mxb;
        float ca = 1.0f + 2.0f * xy + y2;
        float cb = 1.0f - x2;
        float den = fmaxf(1.0f + 2.0f * xy + x2 * y2, MINN);
        float alpha = ca * s1p / den;
        float beta  = cb / den;
        // ||h||^2 analytically
        float hn2 = alpha * alpha * mxn2 + 2.0f * alpha * beta * mxb + beta * beta * y2;
        float hn  = fmaxf(sqrtf(hn2), MINN);
        float ps2 = (hn > MAXN) ? MAXN / hn : 1.0f;
        float hnc = fmaxf(fminf(hn, MAXN), MINN);        // ||h|| after proj
        float ls  = artanh_clip(hnc) / hnc;              // logmap0 scale
        float F   = ls * ps2;
        float A = F * alpha, B = F * beta;
        int rr = row0 + lr;
        if (rr < N) {
            ushort o[4];
#pragma unroll
            for (int j = 0; j < 4; ++j) o[j] = f2bf(A * acc[i][j] + B * b[j]);
            *(uint2*)(XT + (size_t)rr * D + ct * 4) =
                make_uint2((uint)o[0] | ((uint)o[1] << 16), (uint)o[2] | ((uint)o[3] << 16));
        }
    }
}

// ---------------- CSR build ----------------
// hist also records each edge's arrival rank within its row
__global__ __launch_bounds__(256)
void hist_kernel(const int* __restrict__ erow, int* __restrict__ cnt,
                 int* __restrict__ rank, int E)
{
    int e = blockIdx.x * 256 + threadIdx.x;
    if (e < E) rank[e] = atomicAdd(&cnt[erow[e]], 1);
}

// block-level partial exclusive scan: 1024 elems/block (256 thr x 4)
__global__ __launch_bounds__(256)
void scan1_kernel(const int* __restrict__ cnt, int* __restrict__ offs,
                  int* __restrict__ bsum, int N)
{
    __shared__ int wsum[4];
    int t = threadIdx.x;
    int base = blockIdx.x * 1024 + t * 4;
    int v[4];
#pragma unroll
    for (int j = 0; j < 4; ++j) v[j] = (base + j < N) ? cnt[base + j] : 0;
    int tt = v[0] + v[1] + v[2] + v[3];
    int incl = tt;
#pragma unroll
    for (int o = 1; o < 64; o <<= 1) {
        int n = __shfl_up(incl, o, 64);
        if ((t & 63) >= o) incl += n;
    }
    if ((t & 63) == 63) wsum[t >> 6] = incl;
    __syncthreads();
    int wbase = 0;
    for (int w = 0; w < (t >> 6); ++w) wbase += wsum[w];
    int ex = wbase + incl - tt;
#pragma unroll
    for (int j = 0; j < 4; ++j) {
        if (base + j < N) offs[base + j] = ex;
        ex += v[j];
    }
    if (t == 255) bsum[blockIdx.x] = wbase + incl;
}

__global__ __launch_bounds__(64)
void scan2_kernel(int* __restrict__ bsum, int nb)
{
    int l = threadIdx.x;
    int v = (l < nb) ? bsum[l] : 0;
    int incl = v;
#pragma unroll
    for (int o = 1; o < 64; o <<= 1) {
        int n = __shfl_up(incl, o, 64);
        if (l >= o) incl += n;
    }
    if (l < nb) bsum[l] = incl - v;
}

__global__ __launch_bounds__(256)
void fix_kernel(int* __restrict__ offs, const int* __restrict__ bsum, int N)
{
    int i = blockIdx.x * 256 + threadIdx.x;
    if (i < N) offs[i] += bsum[i >> 10];
}

// atomic-free fill: position = offs[row] + rank (rank captured in hist)
__global__ __launch_bounds__(256)
void fill_kernel(const int* __restrict__ erow, const int* __restrict__ ecol,
                 const float* __restrict__ adj, const int* __restrict__ rank,
                 const int* __restrict__ offs, int2* __restrict__ bpack, int E)
{
    int e = blockIdx.x * 256 + threadIdx.x;
    if (e >= E) return;
    int p = offs[erow[e]] + rank[e];
    bpack[p] = make_int2(ecol[e], __float_as_int(adj[e]));
}

// ------- gather (bf16 rows) + fused HypAct tail: one wave per row -------
__global__ __launch_bounds__(256)
void gather_kernel(const ushort* __restrict__ XT, const int2* __restrict__ bpack,
                   const int* __restrict__ offs, const int* __restrict__ cnt,
                   float* __restrict__ OUT, int N)
{
    int row = blockIdx.x * 4 + (threadIdx.x >> 6);
    int lane = threadIdx.x & 63;
    if (row >= N) return;
    int start = offs[row], deg = cnt[row];
    float a0 = 0.f, a1 = 0.f, b0 = 0.f, b1 = 0.f;
    int i = 0;
    for (; i + 1 < deg; i += 2) {
        int2 e0 = bpack[start + i];
        int2 e1 = bpack[start + i + 1];
        float v0 = __int_as_float(e0.y), v1 = __int_as_float(e1.y);
        uint u0 = ((const uint*)(XT + (size_t)e0.x * D))[lane];
        uint u1 = ((const uint*)(XT + (size_t)e1.x * D))[lane];
        a0 += v0 * __uint_as_float((u0 & 0xffffu) << 16);
        a1 += v0 * __uint_as_float(u0 & 0xffff0000u);
        b0 += v1 * __uint_as_float((u1 & 0xffffu) << 16);
        b1 += v1 * __uint_as_float(u1 & 0xffff0000u);
    }
    if (i < deg) {
        int2 e0 = bpack[start + i];
        float v = __int_as_float(e0.y);
        uint u0 = ((const uint*)(XT + (size_t)e0.x * D))[lane];
        a0 += v * __uint_as_float((u0 & 0xffffu) << 16);
        a1 += v * __uint_as_float(u0 & 0xffff0000u);
    }
    float tx = fminf(a0 + b0, MAX_NORM);
    float ty = fminf(a1 + b1, MAX_NORM);
    // expmap0 + proj
    float nt = fmaxf(sqrtf(wave_sum(tx * tx + ty * ty)), MINN);
    float es = tanhf(nt) / nt;
    float h0 = es * tx, h1 = es * ty;
    float hn = fmaxf(sqrtf(wave_sum(h0 * h0 + h1 * h1)), MINN);
    if (hn > MAXN) { float f = MAXN / hn; h0 *= f; h1 *= f; }
    // logmap0 + relu + clamp
    float hn2 = fmaxf(sqrtf(wave_sum(h0 * h0 + h1 * h1)), MINN);
    float ls = artanh_clip(hn2) / hn2;
    float u0 = fminf(fmaxf(ls * h0, 0.0f), MAX_NORM);
    float u1 = fminf(fmaxf(ls * h1, 0.0f), MAX_NORM);
    // expmap0
    float un = fmaxf(sqrtf(wave_sum(u0 * u0 + u1 * u1)), MINN);
    float os = tanhf(un) / un;
    float2 o; o.x = os * u0; o.y = os * u1;
    ((float2*)(OUT + (size_t)row * D))[lane] = o;
}

extern "C" void kernel_launch(void* const* d_in, const int* in_sizes, int n_in,
                              void* d_out, int out_size, void* d_ws, size_t ws_size,
                              hipStream_t stream)
{
    const float* x    = (const float*)d_in[0];
    const float* adj  = (const float*)d_in[1];
    const float* W    = (const float*)d_in[2];
    const float* bias = (const float*)d_in[3];
    const int*   erow = (const int*)d_in[4];
    const int*   ecol = (const int*)d_in[5];
    float* out = (float*)d_out;
    const int N = in_sizes[0] / D;
    const int E = in_sizes[1];

    // workspace layout (256B aligned segments)
    char* p = (char*)d_ws;
    size_t off = 0;
    auto alloc = [&](size_t bytes) {
        char* r = p + off;
        off = (off + bytes + 255) & ~(size_t)255;
        return r;
    };
    ushort* xt  = (ushort*)alloc((size_t)N * D * sizeof(ushort));
    int*   cnt  = (int*)  alloc((size_t)N * sizeof(int));
    int*   offs = (int*)  alloc((size_t)N * sizeof(int));
    int*   bsum = (int*)  alloc(256 * sizeof(int));
    int*   rank = (int*)  alloc((size_t)E * sizeof(int));
    int2*  bpack= (int2*) alloc((size_t)E * sizeof(int2));
    (void)ws_size;

    // CSR build chain is independent of the GEMM; stream serializes them anyway
    hipMemsetAsync(cnt, 0, (size_t)N * sizeof(int), stream);
    gemm_kernel<<<(N + 31) / 32, 256, 0, stream>>>(x, W, bias, xt, N);
    hist_kernel<<<(E + 255) / 256, 256, 0, stream>>>(erow, cnt, rank, E);
    int nb = (N + 1023) / 1024;   // 49 for N=50000, must be <= 64
    scan1_kernel<<<nb, 256, 0, stream>>>(cnt, offs, bsum, N);
    scan2_kernel<<<1, 64, 0, stream>>>(bsum, nb);
    fix_kernel<<<(N + 255) / 256, 256, 0, stream>>>(offs, bsum, N);
    fill_kernel<<<(E + 255) / 256, 256, 0, stream>>>(erow, ecol, adj, rank, offs, bpack, E);
    gather_kernel<<<(N + 3) / 4, 256, 0, stream>>>(xt, bpack, offs, cnt, out, N);
}

// Round 5
// 150.232 us; speedup vs baseline: 9.5948x; 1.0826x over previous
//
#include <hip/hip_runtime.h>

#define D 128
#define MAXN 0.996f            // (1 - BALL_EPS) / sqrt(c), c = 1
#define MINN 1e-15f
#define ARTANH_MAX (1.0f - 1e-7f)
#define MAX_NORM 1e6f

typedef unsigned int uint;
typedef unsigned short ushort;

__device__ __forceinline__ float wave_sum(float v) {
#pragma unroll
    for (int o = 32; o > 0; o >>= 1) v += __shfl_xor(v, o, 64);
    return v;
}

// reduce across an aligned 32-lane group (stays inside each half of a wave64)
__device__ __forceinline__ float half_sum(float v) {
#pragma unroll
    for (int o = 16; o > 0; o >>= 1) v += __shfl_xor(v, o, 64);
    return v;
}

__device__ __forceinline__ float artanh_clip(float x) {
    x = fminf(fmaxf(x, -ARTANH_MAX), ARTANH_MAX);
    return 0.5f * logf((1.0f + x) / (1.0f - x));
}

__device__ __forceinline__ ushort f2bf(float f) {   // RNE, finite inputs
    uint u = __float_as_uint(f);
    return (ushort)((u + 0x7fffu + ((u >> 16) & 1u)) >> 16);
}

// ---- GEMM + fused HypLinear: xt[i][:] = A_i * (x_i @ W^T) + B_i * b_hyp, bf16 out ----
__global__ __launch_bounds__(256)
void gemm_kernel(const float* __restrict__ X, const float* __restrict__ W,
                 const float* __restrict__ bias, ushort* __restrict__ XT, int N)
{
    __shared__ float xs[32][36];    // xs[k][r] (transposed), padded
    __shared__ float wl[32][132];   // wl[k][c], padded
    __shared__ float xn2s[32];      // ||x_row||^2
    const int tid = threadIdx.x;
    const int row0 = blockIdx.x * 32;
    const int ct = tid & 31;        // col group: cols ct*4..+3
    const int rt = tid >> 5;        // row group: rows rt*4..+3
    float acc[4][4] = {{0.f}};
    float xsq = 0.f;                // partial ||x_row||^2 for staging row tid>>3

    for (int k0 = 0; k0 < D; k0 += 32) {
        {
            int r = tid >> 3;
            int kq = (tid & 7) * 4;
            int rr = row0 + r;
            float4 v = make_float4(0.f, 0.f, 0.f, 0.f);
            if (rr < N) v = *(const float4*)(X + (size_t)rr * D + k0 + kq);
            xsq += v.x * v.x + v.y * v.y + v.z * v.z + v.w * v.w;
            xs[kq + 0][r] = v.x; xs[kq + 1][r] = v.y;
            xs[kq + 2][r] = v.z; xs[kq + 3][r] = v.w;
        }
        {
            int c = tid >> 1;
            int kh = (tid & 1) * 16;
            const float* wp = W + (size_t)c * D + k0 + kh;
#pragma unroll
            for (int i = 0; i < 16; i += 4) {
                float4 v = *(const float4*)(wp + i);
                wl[kh + i + 0][c] = v.x; wl[kh + i + 1][c] = v.y;
                wl[kh + i + 2][c] = v.z; wl[kh + i + 3][c] = v.w;
            }
        }
        __syncthreads();
#pragma unroll
        for (int k = 0; k < 32; ++k) {
            float4 a = *(const float4*)&xs[k][rt * 4];
            float4 b = *(const float4*)&wl[k][ct * 4];
            acc[0][0] += a.x * b.x; acc[0][1] += a.x * b.y; acc[0][2] += a.x * b.z; acc[0][3] += a.x * b.w;
            acc[1][0] += a.y * b.x; acc[1][1] += a.y * b.y; acc[1][2] += a.y * b.z; acc[1][3] += a.y * b.w;
            acc[2][0] += a.z * b.x; acc[2][1] += a.z * b.y; acc[2][2] += a.z * b.z; acc[2][3] += a.z * b.w;
            acc[3][0] += a.w * b.x; acc[3][1] += a.w * b.y; acc[3][2] += a.w * b.z; acc[3][3] += a.w * b.w;
        }
        __syncthreads();
    }
    // ||x_row||^2: reduce over the 8 staging lanes of each row, park in LDS
    xsq += __shfl_xor(xsq, 1, 64);
    xsq += __shfl_xor(xsq, 2, 64);
    xsq += __shfl_xor(xsq, 4, 64);
    if ((tid & 7) == 0) xn2s[tid >> 3] = xsq;

    // hyp bias: b = proj(expmap0(bias)); per thread holds cols ct*4..+3
    float4 bv = *(const float4*)(bias + ct * 4);
    float bsq = half_sum(bv.x * bv.x + bv.y * bv.y + bv.z * bv.z + bv.w * bv.w);
    float bn = fmaxf(sqrtf(bsq), MINN);
    float bt = tanhf(bn);                       // ||expmap0(bias)||
    float bps = (bt > MAXN) ? MAXN / fmaxf(bt, MINN) : 1.0f;
    float bsc = bt / bn * bps;
    float b[4] = { bsc * bv.x, bsc * bv.y, bsc * bv.z, bsc * bv.w };
    float bhn = fminf(fmaxf(bt, MINN), MAXN);   // ||b|| after proj
    float y2 = bhn * bhn;
    __syncthreads();                            // xn2s ready

#pragma unroll
    for (int i = 0; i < 4; ++i) {
        int lr = rt * 4 + i;                    // local row 0..31
        float mxn2 = acc[i][0]*acc[i][0] + acc[i][1]*acc[i][1] + acc[i][2]*acc[i][2] + acc[i][3]*acc[i][3];
        float mxb  = acc[i][0]*b[0] + acc[i][1]*b[1] + acc[i][2]*b[2] + acc[i][3]*b[3];
        mxn2 = half_sum(mxn2);
        mxb  = half_sum(mxb);
        // mobius_matvec tail + proj
        float xn  = fmaxf(sqrtf(xn2s[lr]), MINN);
        float mxn = fmaxf(sqrtf(mxn2), MINN);
        float t1  = tanhf(mxn / xn * artanh_clip(xn));   // ||res||
        float s1  = t1 / mxn;                            // res = s1*mx
        float ps1 = (t1 > MAXN) ? MAXN / fmaxf(t1, MINN) : 1.0f;
        float s1p = s1 * ps1;
        float rn  = fminf(fmaxf(t1, MINN), MAXN);
        // mobius_add(res, b):  h = alpha*mx + beta*b
        float x2 = rn * rn;
        float xy = s1p * mxb;
        float ca = 1.0f + 2.0f * xy + y2;
        float cb = 1.0f - x2;
        float den = fmaxf(1.0f + 2.0f * xy + x2 * y2, MINN);
        float alpha = ca * s1p / den;
        float beta  = cb / den;
        // ||h||^2 analytically
        float hn2 = alpha * alpha * mxn2 + 2.0f * alpha * beta * mxb + beta * beta * y2;
        float hn  = fmaxf(sqrtf(hn2), MINN);
        float ps2 = (hn > MAXN) ? MAXN / hn : 1.0f;
        float hnc = fmaxf(fminf(hn, MAXN), MINN);        // ||h|| after proj
        float ls  = artanh_clip(hnc) / hnc;              // logmap0 scale
        float F   = ls * ps2;
        float A = F * alpha, B = F * beta;
        int rr = row0 + lr;
        if (rr < N) {
            ushort o[4];
#pragma unroll
            for (int j = 0; j < 4; ++j) o[j] = f2bf(A * acc[i][j] + B * b[j]);
            *(uint2*)(XT + (size_t)rr * D + ct * 4) =
                make_uint2((uint)o[0] | ((uint)o[1] << 16), (uint)o[2] | ((uint)o[3] << 16));
        }
    }
}

// ---------------- CSR build ----------------
// hist also records each edge's arrival rank within its row
__global__ __launch_bounds__(256)
void hist_kernel(const int* __restrict__ erow, int* __restrict__ cnt,
                 int* __restrict__ rank, int E)
{
    int e = blockIdx.x * 256 + threadIdx.x;
    if (e < E) rank[e] = atomicAdd(&cnt[erow[e]], 1);
}

// block-level partial exclusive scan: 1024 elems/block (256 thr x 4)
__global__ __launch_bounds__(256)
void scan1_kernel(const int* __restrict__ cnt, int* __restrict__ offs,
                  int* __restrict__ bsum, int N)
{
    __shared__ int wsum[4];
    int t = threadIdx.x;
    int base = blockIdx.x * 1024 + t * 4;
    int v[4];
#pragma unroll
    for (int j = 0; j < 4; ++j) v[j] = (base + j < N) ? cnt[base + j] : 0;
    int tt = v[0] + v[1] + v[2] + v[3];
    int incl = tt;
#pragma unroll
    for (int o = 1; o < 64; o <<= 1) {
        int n = __shfl_up(incl, o, 64);
        if ((t & 63) >= o) incl += n;
    }
    if ((t & 63) == 63) wsum[t >> 6] = incl;
    __syncthreads();
    int wbase = 0;
    for (int w = 0; w < (t >> 6); ++w) wbase += wsum[w];
    int ex = wbase + incl - tt;
#pragma unroll
    for (int j = 0; j < 4; ++j) {
        if (base + j < N) offs[base + j] = ex;
        ex += v[j];
    }
    if (t == 255) bsum[blockIdx.x] = wbase + incl;
}

__global__ __launch_bounds__(64)
void scan2_kernel(int* __restrict__ bsum, int nb)
{
    int l = threadIdx.x;
    int v = (l < nb) ? bsum[l] : 0;
    int incl = v;
#pragma unroll
    for (int o = 1; o < 64; o <<= 1) {
        int n = __shfl_up(incl, o, 64);
        if (l >= o) incl += n;
    }
    if (l < nb) bsum[l] = incl - v;
}

__global__ __launch_bounds__(256)
void fix_kernel(int* __restrict__ offs, const int* __restrict__ bsum, int N, int E)
{
    int i = blockIdx.x * 256 + threadIdx.x;
    if (i < N) offs[i] += bsum[i >> 10];
    if (i == 0) offs[N] = E;
}

// atomic-free fill: position = offs[row] + rank; 4-byte packed edge (col16 | val-bf16)
__global__ __launch_bounds__(256)
void fill_kernel(const int* __restrict__ erow, const int* __restrict__ ecol,
                 const float* __restrict__ adj, const int* __restrict__ rank,
                 const int* __restrict__ offs, uint* __restrict__ bpack, int E)
{
    int e = blockIdx.x * 256 + threadIdx.x;
    if (e >= E) return;
    int p = offs[erow[e]] + rank[e];
    bpack[p] = ((uint)ecol[e] << 16) | (uint)f2bf(adj[e]);
}

// ------- gather (bf16 rows, 4B edges) + fused HypAct tail: one wave per row -------
__global__ __launch_bounds__(256)
void gather_kernel(const ushort* __restrict__ XT, const uint* __restrict__ bpack,
                   const int* __restrict__ offs, float* __restrict__ OUT, int N)
{
    int row = blockIdx.x * 4 + (threadIdx.x >> 6);
    int lane = threadIdx.x & 63;
    if (row >= N) return;
    int start = offs[row], end = offs[row + 1];
    const uint* xtw = (const uint*)XT;   // 1 uint = 2 bf16 cols per lane
    float a0 = 0.f, a1 = 0.f, b0 = 0.f, b1 = 0.f;
    float c0 = 0.f, c1 = 0.f, d0 = 0.f, d1 = 0.f;
    int i = start;
    for (; i + 3 < end; i += 4) {
        uint4 q = *(const uint4*)(bpack + i);   // wave-uniform 16B load, 4 edges
        float v0 = __uint_as_float(q.x << 16);
        float v1 = __uint_as_float(q.y << 16);
        float v2 = __uint_as_float(q.z << 16);
        float v3 = __uint_as_float(q.w << 16);
        uint u0 = xtw[(size_t)(q.x >> 16) * 64 + lane];
        uint u1 = xtw[(size_t)(q.y >> 16) * 64 + lane];
        uint u2 = xtw[(size_t)(q.z >> 16) * 64 + lane];
        uint u3 = xtw[(size_t)(q.w >> 16) * 64 + lane];
        a0 += v0 * __uint_as_float(u0 << 16);
        a1 += v0 * __uint_as_float(u0 & 0xffff0000u);
        b0 += v1 * __uint_as_float(u1 << 16);
        b1 += v1 * __uint_as_float(u1 & 0xffff0000u);
        c0 += v2 * __uint_as_float(u2 << 16);
        c1 += v2 * __uint_as_float(u2 & 0xffff0000u);
        d0 += v3 * __uint_as_float(u3 << 16);
        d1 += v3 * __uint_as_float(u3 & 0xffff0000u);
    }
    for (; i < end; ++i) {
        uint q = bpack[i];
        float v = __uint_as_float(q << 16);
        uint u = xtw[(size_t)(q >> 16) * 64 + lane];
        a0 += v * __uint_as_float(u << 16);
        a1 += v * __uint_as_float(u & 0xffff0000u);
    }
    float tx = fminf((a0 + b0) + (c0 + d0), MAX_NORM);
    float ty = fminf((a1 + b1) + (c1 + d1), MAX_NORM);
    // expmap0 + proj
    float nt = fmaxf(sqrtf(wave_sum(tx * tx + ty * ty)), MINN);
    float es = tanhf(nt) / nt;
    float h0 = es * tx, h1 = es * ty;
    float hn = fmaxf(sqrtf(wave_sum(h0 * h0 + h1 * h1)), MINN);
    if (hn > MAXN) { float f = MAXN / hn; h0 *= f; h1 *= f; }
    // logmap0 + relu + clamp
    float hn2 = fmaxf(sqrtf(wave_sum(h0 * h0 + h1 * h1)), MINN);
    float ls = artanh_clip(hn2) / hn2;
    float u0 = fminf(fmaxf(ls * h0, 0.0f), MAX_NORM);
    float u1 = fminf(fmaxf(ls * h1, 0.0f), MAX_NORM);
    // expmap0
    float un = fmaxf(sqrtf(wave_sum(u0 * u0 + u1 * u1)), MINN);
    float os = tanhf(un) / un;
    float2 o; o.x = os * u0; o.y = os * u1;
    ((float2*)(OUT + (size_t)row * D))[lane] = o;
}

extern "C" void kernel_launch(void* const* d_in, const int* in_sizes, int n_in,
                              void* d_out, int out_size, void* d_ws, size_t ws_size,
                              hipStream_t stream)
{
    const float* x    = (const float*)d_in[0];
    const float* adj  = (const float*)d_in[1];
    const float* W    = (const float*)d_in[2];
    const float* bias = (const float*)d_in[3];
    const int*   erow = (const int*)d_in[4];
    const int*   ecol = (const int*)d_in[5];
    float* out = (float*)d_out;
    const int N = in_sizes[0] / D;   // 50000 (< 65536: col fits 16 bits in bpack)
    const int E = in_sizes[1];

    // workspace layout (256B aligned segments)
    char* p = (char*)d_ws;
    size_t off = 0;
    auto alloc = [&](size_t bytes) {
        char* r = p + off;
        off = (off + bytes + 255) & ~(size_t)255;
        return r;
    };
    ushort* xt  = (ushort*)alloc((size_t)N * D * sizeof(ushort));
    int*   cnt  = (int*)  alloc((size_t)N * sizeof(int));
    int*   offs = (int*)  alloc(((size_t)N + 1) * sizeof(int));
    int*   bsum = (int*)  alloc(256 * sizeof(int));
    int*   rank = (int*)  alloc((size_t)E * sizeof(int));
    uint*  bpack= (uint*) alloc((size_t)E * sizeof(uint));
    (void)ws_size;

    hipMemsetAsync(cnt, 0, (size_t)N * sizeof(int), stream);
    gemm_kernel<<<(N + 31) / 32, 256, 0, stream>>>(x, W, bias, xt, N);
    hist_kernel<<<(E + 255) / 256, 256, 0, stream>>>(erow, cnt, rank, E);
    int nb = (N + 1023) / 1024;   // 49 for N=50000, must be <= 64
    scan1_kernel<<<nb, 256, 0, stream>>>(cnt, offs, bsum, N);
    scan2_kernel<<<1, 64, 0, stream>>>(bsum, nb);
    fix_kernel<<<(N + 255) / 256, 256, 0, stream>>>(offs, bsum, N, E);
    fill_kernel<<<(E + 255) / 256, 256, 0, stream>>>(erow, ecol, adj, rank, offs, bpack, E);
    gather_kernel<<<(N + 3) / 4, 256, 0, stream>>>(xt, bpack, offs, out, N);
}

// Round 6
// 145.395 us; speedup vs baseline: 9.9140x; 1.0333x over previous
//
#include <hip/hip_runtime.h>

#define D 128
#define MAXN 0.996f            // (1 - BALL_EPS) / sqrt(c), c = 1
#define MINN 1e-15f
#define ARTANH_MAX (1.0f - 1e-7f)
#define MAX_NORM 1e6f

typedef unsigned int uint;
typedef unsigned short ushort;
typedef __bf16 bf16x8 __attribute__((ext_vector_type(8)));
typedef float f32x4 __attribute__((ext_vector_type(4)));

__device__ __forceinline__ float wave_sum(float v) {
#pragma unroll
    for (int o = 32; o > 0; o >>= 1) v += __shfl_xor(v, o, 64);
    return v;
}

__device__ __forceinline__ float quad_sum(float v) {   // sum lanes l, l^16, l^32, l^48
    v += __shfl_xor(v, 16, 64);
    v += __shfl_xor(v, 32, 64);
    return v;
}

__device__ __forceinline__ float artanh_clip(float x) {
    x = fminf(fmaxf(x, -ARTANH_MAX), ARTANH_MAX);
    return 0.5f * logf((1.0f + x) / (1.0f - x));
}

__device__ __forceinline__ ushort f2bf(float f) {   // RNE, finite inputs
    uint u = __float_as_uint(f);
    return (ushort)((u + 0x7fffu + ((u >> 16) & 1u)) >> 16);
}

__device__ __forceinline__ uint pk2(float a, float b) {
    return (uint)f2bf(a) | ((uint)f2bf(b) << 16);
}

// ---------------- W fp32 -> bf16 (once; 128x128 = 32KB) ----------------
__global__ __launch_bounds__(256)
void wconv_kernel(const float* __restrict__ W, ushort* __restrict__ WB)
{
    int i = blockIdx.x * 256 + threadIdx.x;   // grid covers 16384
    WB[i] = f2bf(W[i]);
}

// ---- MFMA GEMM + fused HypLinear: xt[m][:] = A_m*(x_m @ W^T) + B_m*b_hyp, bf16 out ----
// Per wave: 16 X-rows. D[i][j] = sum_k W[i][k]*X[j][k]  (i = out col, j = out row).
// A-frag = W rows (bf16), B-frag = X rows (cvt on the fly). No LDS.
// Frag k-map (16x16x32): elem e <-> k = (e&3) + 4*(lane>>4) + 16*(e>>2).
// C/D map: Dcol j = lane&15, Drow i = (lane>>4)*4 + reg   [m89-verified].
__global__ __launch_bounds__(256)
void gemm_mfma_kernel(const float* __restrict__ X, const ushort* __restrict__ WB,
                      const float* __restrict__ bias, ushort* __restrict__ XT, int N)
{
    const int wid = threadIdx.x >> 6;
    const int l   = threadIdx.x & 63;
    const int m0  = (blockIdx.x * 4 + wid) * 16;
    if (m0 >= N) return;
    const int lr = l & 15;          // X row within tile == D col j
    const int kg = l >> 4;          // k-group
    const int row = m0 + lr;
    const int rowc = row < N ? row : N - 1;

    // ---- B-frags (X rows) + ||x_row||^2 partial ----
    const float* xp = X + (size_t)rowc * D + kg * 4;
    bf16x8 bfr[4];
    float xsq = 0.f;
#pragma unroll
    for (int ks = 0; ks < 4; ++ks) {
        float4 v0 = *(const float4*)(xp + ks * 32);
        float4 v1 = *(const float4*)(xp + ks * 32 + 16);
        xsq += v0.x*v0.x + v0.y*v0.y + v0.z*v0.z + v0.w*v0.w
             + v1.x*v1.x + v1.y*v1.y + v1.z*v1.z + v1.w*v1.w;
        uint4 bq = make_uint4(pk2(v0.x, v0.y), pk2(v0.z, v0.w),
                              pk2(v1.x, v1.y), pk2(v1.z, v1.w));
        bfr[ks] = __builtin_bit_cast(bf16x8, bq);
    }
    xsq = quad_sum(xsq);            // full ||x_row||^2, row = m0+lr

    // ---- bias values for this lane's output cols: n = t*16 + kg*4 + r ----
    float4 bb[8];
    float bsq = 0.f;
#pragma unroll
    for (int t = 0; t < 8; ++t) {
        bb[t] = *(const float4*)(bias + t * 16 + kg * 4);
        bsq += bb[t].x*bb[t].x + bb[t].y*bb[t].y + bb[t].z*bb[t].z + bb[t].w*bb[t].w;
    }
    bsq = quad_sum(bsq);            // ||bias||^2 (replicated)
    float bn  = fmaxf(sqrtf(bsq), MINN);
    float bt  = tanhf(bn);
    float bps = (bt > MAXN) ? MAXN / fmaxf(bt, MINN) : 1.0f;
    float bsc = bt / bn * bps;      // b_hyp = bsc * bias
    float bhn = fminf(fmaxf(bt * bps, MINN), MAXN);
    float y2  = bhn * bhn;

    // ---- MFMA main: acc[t] = 16x16 tile (W rows t*16..+15) x (X rows m0..m0+15) ----
    f32x4 acc[8];
#pragma unroll
    for (int t = 0; t < 8; ++t) acc[t] = (f32x4){0.f, 0.f, 0.f, 0.f};
#pragma unroll
    for (int ks = 0; ks < 4; ++ks) {
#pragma unroll
        for (int t = 0; t < 8; ++t) {
            const ushort* wrow = WB + (size_t)(t * 16 + lr) * D + ks * 32 + kg * 4;
            uint2 wlo = *(const uint2*)(wrow);
            uint2 whi = *(const uint2*)(wrow + 16);
            uint4 wv = make_uint4(wlo.x, wlo.y, whi.x, whi.y);
            bf16x8 af = __builtin_bit_cast(bf16x8, wv);
            acc[t] = __builtin_amdgcn_mfma_f32_16x16x32_bf16(af, bfr[ks], acc[t], 0, 0, 0);
        }
    }

    // ---- row reductions: ||mx||^2 and <mx, bias> ----
    float sacc = 0.f, sab = 0.f;
#pragma unroll
    for (int t = 0; t < 8; ++t) {
        sacc += acc[t][0]*acc[t][0] + acc[t][1]*acc[t][1] + acc[t][2]*acc[t][2] + acc[t][3]*acc[t][3];
        sab  += acc[t][0]*bb[t].x + acc[t][1]*bb[t].y + acc[t][2]*bb[t].z + acc[t][3]*bb[t].w;
    }
    sacc = quad_sum(sacc);
    sab  = quad_sum(sab);

    // ---- HypLinear scalar tail (per output row) ----
    float xn  = fmaxf(sqrtf(xsq), MINN);
    float mxn = fmaxf(sqrtf(sacc), MINN);
    float t1  = tanhf(mxn / xn * artanh_clip(xn));    // ||res||
    float s1  = t1 / mxn;
    float ps1 = (t1 > MAXN) ? MAXN / fmaxf(t1, MINN) : 1.0f;
    float s1p = s1 * ps1;
    float rn  = fminf(fmaxf(t1, MINN), MAXN);
    float x2  = rn * rn;
    float mxb = bsc * sab;
    float xy  = s1p * mxb;
    float ca  = 1.0f + 2.0f * xy + y2;
    float cb  = 1.0f - x2;
    float den = fmaxf(1.0f + 2.0f * xy + x2 * y2, MINN);
    float alpha = ca * s1p / den;
    float beta  = cb / den;
    float hn2 = alpha * alpha * sacc + 2.0f * alpha * beta * mxb + beta * beta * y2;
    float hn  = fmaxf(sqrtf(hn2), MINN);
    float ps2 = (hn > MAXN) ? MAXN / hn : 1.0f;
    float hnc = fmaxf(fminf(hn, MAXN), MINN);
    float ls  = artanh_clip(hnc) / hnc;
    float F   = ls * ps2;
    float A = F * alpha, Bc = F * beta * bsc;

    if (row < N) {
        ushort* op = XT + (size_t)row * D + kg * 4;
#pragma unroll
        for (int t = 0; t < 8; ++t) {
            uint2 o = make_uint2(pk2(A * acc[t][0] + Bc * bb[t].x, A * acc[t][1] + Bc * bb[t].y),
                                 pk2(A * acc[t][2] + Bc * bb[t].z, A * acc[t][3] + Bc * bb[t].w));
            *(uint2*)(op + t * 16) = o;
        }
    }
}

// ---------------- CSR build ----------------
__global__ __launch_bounds__(256)
void hist_kernel(const int* __restrict__ erow, int* __restrict__ cnt,
                 int* __restrict__ rank, int E)
{
    int e = blockIdx.x * 256 + threadIdx.x;
    if (e < E) rank[e] = atomicAdd(&cnt[erow[e]], 1);
}

// block-level partial exclusive scan: 1024 elems/block (256 thr x 4)
__global__ __launch_bounds__(256)
void scan1_kernel(const int* __restrict__ cnt, int* __restrict__ offs,
                  int* __restrict__ bsum, int N)
{
    __shared__ int wsum[4];
    int t = threadIdx.x;
    int base = blockIdx.x * 1024 + t * 4;
    int v[4];
#pragma unroll
    for (int j = 0; j < 4; ++j) v[j] = (base + j < N) ? cnt[base + j] : 0;
    int tt = v[0] + v[1] + v[2] + v[3];
    int incl = tt;
#pragma unroll
    for (int o = 1; o < 64; o <<= 1) {
        int n = __shfl_up(incl, o, 64);
        if ((t & 63) >= o) incl += n;
    }
    if ((t & 63) == 63) wsum[t >> 6] = incl;
    __syncthreads();
    int wbase = 0;
    for (int w = 0; w < (t >> 6); ++w) wbase += wsum[w];
    int ex = wbase + incl - tt;
#pragma unroll
    for (int j = 0; j < 4; ++j) {
        if (base + j < N) offs[base + j] = ex;
        ex += v[j];
    }
    if (t == 255) bsum[blockIdx.x] = wbase + incl;
}

__global__ __launch_bounds__(64)
void scan2_kernel(int* __restrict__ bsum, int nb)
{
    int l = threadIdx.x;
    int v = (l < nb) ? bsum[l] : 0;
    int incl = v;
#pragma unroll
    for (int o = 1; o < 64; o <<= 1) {
        int n = __shfl_up(incl, o, 64);
        if (l >= o) incl += n;
    }
    if (l < nb) bsum[l] = incl - v;
}

// atomic-free fill: position = offs[row]+bsum[chunk]+rank; 4B packed edge (col16|val-bf16)
__global__ __launch_bounds__(256)
void fill_kernel(const int* __restrict__ erow, const int* __restrict__ ecol,
                 const float* __restrict__ adj, const int* __restrict__ rank,
                 const int* __restrict__ offs, const int* __restrict__ bsum,
                 uint* __restrict__ bpack, int E)
{
    int e = blockIdx.x * 256 + threadIdx.x;
    if (e >= E) return;
    int r = erow[e];
    int p = offs[r] + bsum[r >> 10] + rank[e];
    bpack[p] = ((uint)ecol[e] << 16) | (uint)f2bf(adj[e]);
}

// ------- gather (bf16 rows, 4B edges, 8-deep ILP) + fused HypAct tail -------
__global__ __launch_bounds__(256)
void gather_kernel(const ushort* __restrict__ XT, const uint* __restrict__ bpack,
                   const int* __restrict__ offs, const int* __restrict__ bsum,
                   const int* __restrict__ cnt, float* __restrict__ OUT, int N)
{
    int row = blockIdx.x * 4 + (threadIdx.x >> 6);
    int lane = threadIdx.x & 63;
    if (row >= N) return;
    int start = offs[row] + bsum[row >> 10];
    int end = start + cnt[row];
    const uint* xtw = (const uint*)XT;   // 1 uint = 2 bf16 cols per lane
    float ax[8] = {0.f, 0.f, 0.f, 0.f, 0.f, 0.f, 0.f, 0.f};
    float ay[8] = {0.f, 0.f, 0.f, 0.f, 0.f, 0.f, 0.f, 0.f};
    int i = start;
    for (; i + 7 < end; i += 8) {
        uint4 qa = *(const uint4*)(bpack + i);       // wave-uniform 16B loads
        uint4 qb = *(const uint4*)(bpack + i + 4);
        uint q[8] = {qa.x, qa.y, qa.z, qa.w, qb.x, qb.y, qb.z, qb.w};
#pragma unroll
        for (int j = 0; j < 8; ++j) {
            uint u = xtw[(size_t)(q[j] >> 16) * 64 + lane];
            float v = __uint_as_float(q[j] << 16);
            ax[j] += v * __uint_as_float(u << 16);
            ay[j] += v * __uint_as_float(u & 0xffff0000u);
        }
    }
    for (; i + 3 < end; i += 4) {
        uint4 qa = *(const uint4*)(bpack + i);
        uint q[4] = {qa.x, qa.y, qa.z, qa.w};
#pragma unroll
        for (int j = 0; j < 4; ++j) {
            uint u = xtw[(size_t)(q[j] >> 16) * 64 + lane];
            float v = __uint_as_float(q[j] << 16);
            ax[j] += v * __uint_as_float(u << 16);
            ay[j] += v * __uint_as_float(u & 0xffff0000u);
        }
    }
    for (; i < end; ++i) {
        uint q = bpack[i];
        float v = __uint_as_float(q << 16);
        uint u = xtw[(size_t)(q >> 16) * 64 + lane];
        ax[0] += v * __uint_as_float(u << 16);
        ay[0] += v * __uint_as_float(u & 0xffff0000u);
    }
    float tx = ((ax[0] + ax[1]) + (ax[2] + ax[3])) + ((ax[4] + ax[5]) + (ax[6] + ax[7]));
    float ty = ((ay[0] + ay[1]) + (ay[2] + ay[3])) + ((ay[4] + ay[5]) + (ay[6] + ay[7]));
    tx = fminf(tx, MAX_NORM);
    ty = fminf(ty, MAX_NORM);
    // expmap0 + proj
    float nt = fmaxf(sqrtf(wave_sum(tx * tx + ty * ty)), MINN);
    float es = tanhf(nt) / nt;
    float h0 = es * tx, h1 = es * ty;
    float hn = fmaxf(sqrtf(wave_sum(h0 * h0 + h1 * h1)), MINN);
    if (hn > MAXN) { float f = MAXN / hn; h0 *= f; h1 *= f; }
    // logmap0 + relu + clamp
    float hn2 = fmaxf(sqrtf(wave_sum(h0 * h0 + h1 * h1)), MINN);
    float ls = artanh_clip(hn2) / hn2;
    float u0 = fminf(fmaxf(ls * h0, 0.0f), MAX_NORM);
    float u1 = fminf(fmaxf(ls * h1, 0.0f), MAX_NORM);
    // expmap0
    float un = fmaxf(sqrtf(wave_sum(u0 * u0 + u1 * u1)), MINN);
    float os = tanhf(un) / un;
    float2 o; o.x = os * u0; o.y = os * u1;
    ((float2*)(OUT + (size_t)row * D))[lane] = o;
}

extern "C" void kernel_launch(void* const* d_in, const int* in_sizes, int n_in,
                              void* d_out, int out_size, void* d_ws, size_t ws_size,
                              hipStream_t stream)
{
    const float* x    = (const float*)d_in[0];
    const float* adj  = (const float*)d_in[1];
    const float* W    = (const float*)d_in[2];
    const float* bias = (const float*)d_in[3];
    const int*   erow = (const int*)d_in[4];
    const int*   ecol = (const int*)d_in[5];
    float* out = (float*)d_out;
    const int N = in_sizes[0] / D;   // 50000 (< 65536: col fits 16 bits in bpack)
    const int E = in_sizes[1];

    // workspace layout (256B aligned segments)
    char* p = (char*)d_ws;
    size_t off = 0;
    auto alloc = [&](size_t bytes) {
        char* r = p + off;
        off = (off + bytes + 255) & ~(size_t)255;
        return r;
    };
    ushort* xt  = (ushort*)alloc((size_t)N * D * sizeof(ushort));
    ushort* wb  = (ushort*)alloc((size_t)D * D * sizeof(ushort));
    int*   cnt  = (int*)  alloc((size_t)N * sizeof(int));
    int*   offs = (int*)  alloc((size_t)N * sizeof(int));
    int*   bsum = (int*)  alloc(256 * sizeof(int));
    int*   rank = (int*)  alloc((size_t)E * sizeof(int));
    uint*  bpack= (uint*) alloc((size_t)E * sizeof(uint));
    (void)ws_size;

    hipMemsetAsync(cnt, 0, (size_t)N * sizeof(int), stream);
    wconv_kernel<<<(D * D) / 256, 256, 0, stream>>>(W, wb);
    gemm_mfma_kernel<<<(N + 63) / 64, 256, 0, stream>>>(x, wb, bias, xt, N);
    hist_kernel<<<(E + 255) / 256, 256, 0, stream>>>(erow, cnt, rank, E);
    int nb = (N + 1023) / 1024;   // 49 for N=50000, must be <= 64
    scan1_kernel<<<nb, 256, 0, stream>>>(cnt, offs, bsum, N);
    scan2_kernel<<<1, 64, 0, stream>>>(bsum, nb);
    fill_kernel<<<(E + 255) / 256, 256, 0, stream>>>(erow, ecol, adj, rank, offs, bsum, bpack, E);
    gather_kernel<<<(N + 3) / 4, 256, 0, stream>>>(xt, bpack, offs, bsum, cnt, out, N);
}

// Round 7
// 119.112 us; speedup vs baseline: 12.1015x; 1.2207x over previous
//
#include <hip/hip_runtime.h>

#define D 128
#define MAXN 0.996f            // (1 - BALL_EPS) / sqrt(c), c = 1
#define MINN 1e-15f
#define ARTANH_MAX (1.0f - 1e-7f)
#define MAX_NORM 1e6f

typedef unsigned int uint;
typedef unsigned short ushort;
typedef __bf16 bf16x8 __attribute__((ext_vector_type(8)));
typedef float f32x4 __attribute__((ext_vector_type(4)));

__device__ __forceinline__ float wave_sum(float v) {
#pragma unroll
    for (int o = 32; o > 0; o >>= 1) v += __shfl_xor(v, o, 64);
    return v;
}

__device__ __forceinline__ float quad_sum(float v) {   // sum lanes l, l^16, l^32, l^48
    v += __shfl_xor(v, 16, 64);
    v += __shfl_xor(v, 32, 64);
    return v;
}

__device__ __forceinline__ float artanh_clip(float x) {
    x = fminf(fmaxf(x, -ARTANH_MAX), ARTANH_MAX);
    return 0.5f * logf((1.0f + x) / (1.0f - x));
}

__device__ __forceinline__ ushort f2bf(float f) {   // RNE, finite inputs
    uint u = __float_as_uint(f);
    return (ushort)((u + 0x7fffu + ((u >> 16) & 1u)) >> 16);
}

__device__ __forceinline__ uint pk2(float a, float b) {
    return (uint)f2bf(a) | ((uint)f2bf(b) << 16);
}

// ---- W fp32 -> bf16, pre-swizzled into MFMA A-frag layout ----
// WF[(ks*8 + t)*64 + l] = 16B frag: W[t*16+lr][ks*32+kg*4 ..+3 , +16..+19], lr=l&15, kg=l>>4
__global__ __launch_bounds__(256)
void wconv_kernel(const float* __restrict__ W, uint4* __restrict__ WF)
{
    int idx = blockIdx.x * 256 + threadIdx.x;   // 2048 total
    int l = idx & 63, rest = idx >> 6;
    int t = rest & 7, ks = rest >> 3;
    int lr = l & 15, kg = l >> 4;
    const float* wrow = W + (size_t)(t * 16 + lr) * D + ks * 32 + kg * 4;
    float4 lo = *(const float4*)(wrow);
    float4 hi = *(const float4*)(wrow + 16);
    WF[idx] = make_uint4(pk2(lo.x, lo.y), pk2(lo.z, lo.w),
                         pk2(hi.x, hi.y), pk2(hi.z, hi.w));
}

// ---- MFMA GEMM + fused HypLinear: xt[m][:] = A_m*(x_m @ W^T) + B_m*b_hyp, bf16 out ----
// Per wave: 16 X-rows. A-frag = pre-swizzled W (coalesced uint4), B-frag = X rows (cvt).
// C/D map: Dcol j = lane&15 (X row), Drow i = (lane>>4)*4 + reg  [verified R5].
__global__ __launch_bounds__(128)
void gemm_mfma_kernel(const float* __restrict__ X, const uint4* __restrict__ WF,
                      const float* __restrict__ bias, ushort* __restrict__ XT, int N)
{
    const int wid = threadIdx.x >> 6;
    const int l   = threadIdx.x & 63;
    const int m0  = (blockIdx.x * 2 + wid) * 16;
    if (m0 >= N) return;
    const int lr = l & 15;          // X row within tile == D col j
    const int kg = l >> 4;          // k-group
    const int row = m0 + lr;
    const int rowc = row < N ? row : N - 1;

    // ---- B-frags (X rows) + ||x_row||^2 partial ----
    const float* xp = X + (size_t)rowc * D + kg * 4;
    bf16x8 bfr[4];
    float xsq = 0.f;
#pragma unroll
    for (int ks = 0; ks < 4; ++ks) {
        float4 v0 = *(const float4*)(xp + ks * 32);
        float4 v1 = *(const float4*)(xp + ks * 32 + 16);
        xsq += v0.x*v0.x + v0.y*v0.y + v0.z*v0.z + v0.w*v0.w
             + v1.x*v1.x + v1.y*v1.y + v1.z*v1.z + v1.w*v1.w;
        uint4 bq = make_uint4(pk2(v0.x, v0.y), pk2(v0.z, v0.w),
                              pk2(v1.x, v1.y), pk2(v1.z, v1.w));
        bfr[ks] = __builtin_bit_cast(bf16x8, bq);
    }
    xsq = quad_sum(xsq);            // full ||x_row||^2, row = m0+lr

    // ---- MFMA main: per ks, 8 batched coalesced A-frag loads then 8 MFMAs ----
    f32x4 acc[8];
#pragma unroll
    for (int t = 0; t < 8; ++t) acc[t] = (f32x4){0.f, 0.f, 0.f, 0.f};
#pragma unroll
    for (int ks = 0; ks < 4; ++ks) {
        uint4 wv[8];
#pragma unroll
        for (int t = 0; t < 8; ++t) wv[t] = WF[(ks * 8 + t) * 64 + l];
#pragma unroll
        for (int t = 0; t < 8; ++t)
            acc[t] = __builtin_amdgcn_mfma_f32_16x16x32_bf16(
                __builtin_bit_cast(bf16x8, wv[t]), bfr[ks], acc[t], 0, 0, 0);
    }

    // ---- bias values for this lane's output cols: n = t*16 + kg*4 + r ----
    float4 bb[8];
    float bsq = 0.f;
#pragma unroll
    for (int t = 0; t < 8; ++t) {
        bb[t] = *(const float4*)(bias + t * 16 + kg * 4);
        bsq += bb[t].x*bb[t].x + bb[t].y*bb[t].y + bb[t].z*bb[t].z + bb[t].w*bb[t].w;
    }
    bsq = quad_sum(bsq);            // ||bias||^2 (replicated)
    float bn  = fmaxf(sqrtf(bsq), MINN);
    float bt  = tanhf(bn);
    float bps = (bt > MAXN) ? MAXN / fmaxf(bt, MINN) : 1.0f;
    float bsc = bt / bn * bps;      // b_hyp = bsc * bias
    float bhn = fminf(fmaxf(bt * bps, MINN), MAXN);
    float y2  = bhn * bhn;

    // ---- row reductions: ||mx||^2 and <mx, bias> ----
    float sacc = 0.f, sab = 0.f;
#pragma unroll
    for (int t = 0; t < 8; ++t) {
        sacc += acc[t][0]*acc[t][0] + acc[t][1]*acc[t][1] + acc[t][2]*acc[t][2] + acc[t][3]*acc[t][3];
        sab  += acc[t][0]*bb[t].x + acc[t][1]*bb[t].y + acc[t][2]*bb[t].z + acc[t][3]*bb[t].w;
    }
    sacc = quad_sum(sacc);
    sab  = quad_sum(sab);

    // ---- HypLinear scalar tail (per output row) ----
    float xn  = fmaxf(sqrtf(xsq), MINN);
    float mxn = fmaxf(sqrtf(sacc), MINN);
    float t1  = tanhf(mxn / xn * artanh_clip(xn));    // ||res||
    float s1  = t1 / mxn;
    float ps1 = (t1 > MAXN) ? MAXN / fmaxf(t1, MINN) : 1.0f;
    float s1p = s1 * ps1;
    float rn  = fminf(fmaxf(t1, MINN), MAXN);
    float x2  = rn * rn;
    float mxb = bsc * sab;
    float xy  = s1p * mxb;
    float ca  = 1.0f + 2.0f * xy + y2;
    float cb  = 1.0f - x2;
    float den = fmaxf(1.0f + 2.0f * xy + x2 * y2, MINN);
    float alpha = ca * s1p / den;
    float beta  = cb / den;
    float hn2 = alpha * alpha * sacc + 2.0f * alpha * beta * mxb + beta * beta * y2;
    float hn  = fmaxf(sqrtf(hn2), MINN);
    float ps2 = (hn > MAXN) ? MAXN / hn : 1.0f;
    float hnc = fmaxf(fminf(hn, MAXN), MINN);
    float ls  = artanh_clip(hnc) / hnc;
    float F   = ls * ps2;
    float A = F * alpha, Bc = F * beta * bsc;

    if (row < N) {
        ushort* op = XT + (size_t)row * D + kg * 4;
#pragma unroll
        for (int t = 0; t < 8; ++t) {
            uint2 o = make_uint2(pk2(A * acc[t][0] + Bc * bb[t].x, A * acc[t][1] + Bc * bb[t].y),
                                 pk2(A * acc[t][2] + Bc * bb[t].z, A * acc[t][3] + Bc * bb[t].w));
            *(uint2*)(op + t * 16) = o;
        }
    }
}

// ---------------- CSR build ----------------
// hist (x4 vectorized): records each edge's arrival rank within its row
__global__ __launch_bounds__(256)
void hist_kernel(const int* __restrict__ erow, int* __restrict__ cnt,
                 int* __restrict__ rank, int E)
{
    int e4 = blockIdx.x * 256 + threadIdx.x;
    int E4 = E >> 2;
    if (e4 < E4) {
        int4 r = ((const int4*)erow)[e4];
        int4 k;
        k.x = atomicAdd(&cnt[r.x], 1);
        k.y = atomicAdd(&cnt[r.y], 1);
        k.z = atomicAdd(&cnt[r.z], 1);
        k.w = atomicAdd(&cnt[r.w], 1);
        ((int4*)rank)[e4] = k;
    }
    if (e4 == 0) {
        for (int i = E4 * 4; i < E; ++i) rank[i] = atomicAdd(&cnt[erow[i]], 1);
    }
}

// block-level partial exclusive scan: 1024 elems/block (256 thr x 4)
__global__ __launch_bounds__(256)
void scan1_kernel(const int* __restrict__ cnt, int* __restrict__ offs,
                  int* __restrict__ bsum, int N)
{
    __shared__ int wsum[4];
    int t = threadIdx.x;
    int base = blockIdx.x * 1024 + t * 4;
    int v[4];
#pragma unroll
    for (int j = 0; j < 4; ++j) v[j] = (base + j < N) ? cnt[base + j] : 0;
    int tt = v[0] + v[1] + v[2] + v[3];
    int incl = tt;
#pragma unroll
    for (int o = 1; o < 64; o <<= 1) {
        int n = __shfl_up(incl, o, 64);
        if ((t & 63) >= o) incl += n;
    }
    if ((t & 63) == 63) wsum[t >> 6] = incl;
    __syncthreads();
    int wbase = 0;
    for (int w = 0; w < (t >> 6); ++w) wbase += wsum[w];
    int ex = wbase + incl - tt;
#pragma unroll
    for (int j = 0; j < 4; ++j) {
        if (base + j < N) offs[base + j] = ex;
        ex += v[j];
    }
    if (t == 255) bsum[blockIdx.x] = wbase + incl;
}

__global__ __launch_bounds__(64)
void scan2_kernel(int* __restrict__ bsum, int nb)
{
    int l = threadIdx.x;
    int v = (l < nb) ? bsum[l] : 0;
    int incl = v;
#pragma unroll
    for (int o = 1; o < 64; o <<= 1) {
        int n = __shfl_up(incl, o, 64);
        if (l >= o) incl += n;
    }
    if (l < nb) bsum[l] = incl - v;
}

// atomic-free fill (x4 vectorized): p = offs[row]+bsum[chunk]+rank; 4B edge (col16|val-bf16)
__global__ __launch_bounds__(256)
void fill_kernel(const int* __restrict__ erow, const int* __restrict__ ecol,
                 const float* __restrict__ adj, const int* __restrict__ rank,
                 const int* __restrict__ offs, const int* __restrict__ bsum,
                 uint* __restrict__ bpack, int E)
{
    int e4 = blockIdx.x * 256 + threadIdx.x;
    int E4 = E >> 2;
    if (e4 < E4) {
        int4   r = ((const int4*)erow)[e4];
        int4   c = ((const int4*)ecol)[e4];
        float4 a = ((const float4*)adj)[e4];
        int4   k = ((const int4*)rank)[e4];
        bpack[offs[r.x] + bsum[r.x >> 10] + k.x] = ((uint)c.x << 16) | (uint)f2bf(a.x);
        bpack[offs[r.y] + bsum[r.y >> 10] + k.y] = ((uint)c.y << 16) | (uint)f2bf(a.y);
        bpack[offs[r.z] + bsum[r.z >> 10] + k.z] = ((uint)c.z << 16) | (uint)f2bf(a.z);
        bpack[offs[r.w] + bsum[r.w >> 10] + k.w] = ((uint)c.w << 16) | (uint)f2bf(a.w);
    }
    if (e4 == 0) {
        for (int i = E4 * 4; i < E; ++i) {
            int r = erow[i];
            bpack[offs[r] + bsum[r >> 10] + rank[i]] = ((uint)ecol[i] << 16) | (uint)f2bf(adj[i]);
        }
    }
}

// ------- gather (bf16 rows, 4B edges, 8-deep ILP) + fused HypAct tail (2 wave_sums) -------
__global__ __launch_bounds__(256)
void gather_kernel(const ushort* __restrict__ XT, const uint* __restrict__ bpack,
                   const int* __restrict__ offs, const int* __restrict__ bsum,
                   const int* __restrict__ cnt, float* __restrict__ OUT, int N)
{
    int row = blockIdx.x * 4 + (threadIdx.x >> 6);
    int lane = threadIdx.x & 63;
    if (row >= N) return;
    int start = offs[row] + bsum[row >> 10];
    int end = start + cnt[row];
    const uint* xtw = (const uint*)XT;   // 1 uint = 2 bf16 cols per lane
    float ax[8] = {0.f, 0.f, 0.f, 0.f, 0.f, 0.f, 0.f, 0.f};
    float ay[8] = {0.f, 0.f, 0.f, 0.f, 0.f, 0.f, 0.f, 0.f};
    int i = start;
    for (; i + 7 < end; i += 8) {
        uint4 qa = *(const uint4*)(bpack + i);       // wave-uniform 16B loads
        uint4 qb = *(const uint4*)(bpack + i + 4);
        uint q[8] = {qa.x, qa.y, qa.z, qa.w, qb.x, qb.y, qb.z, qb.w};
#pragma unroll
        for (int j = 0; j < 8; ++j) {
            uint u = xtw[(size_t)(q[j] >> 16) * 64 + lane];
            float v = __uint_as_float(q[j] << 16);
            ax[j] += v * __uint_as_float(u << 16);
            ay[j] += v * __uint_as_float(u & 0xffff0000u);
        }
    }
    for (; i + 3 < end; i += 4) {
        uint4 qa = *(const uint4*)(bpack + i);
        uint q[4] = {qa.x, qa.y, qa.z, qa.w};
#pragma unroll
        for (int j = 0; j < 4; ++j) {
            uint u = xtw[(size_t)(q[j] >> 16) * 64 + lane];
            float v = __uint_as_float(q[j] << 16);
            ax[j] += v * __uint_as_float(u << 16);
            ay[j] += v * __uint_as_float(u & 0xffff0000u);
        }
    }
    for (; i < end; ++i) {
        uint q = bpack[i];
        float v = __uint_as_float(q << 16);
        uint u = xtw[(size_t)(q >> 16) * 64 + lane];
        ax[0] += v * __uint_as_float(u << 16);
        ay[0] += v * __uint_as_float(u & 0xffff0000u);
    }
    float tx = ((ax[0] + ax[1]) + (ax[2] + ax[3])) + ((ax[4] + ax[5]) + (ax[6] + ax[7]));
    float ty = ((ay[0] + ay[1]) + (ay[2] + ay[3])) + ((ay[4] + ay[5]) + (ay[6] + ay[7]));
    tx = fminf(tx, MAX_NORM);
    ty = fminf(ty, MAX_NORM);
    // expmap0 + proj + logmap0 with analytic norms: ||expmap0(t)|| = tanh(||t||)
    float nt = fmaxf(sqrtf(wave_sum(tx * tx + ty * ty)), MINN);
    float th = tanhf(nt);
    float es = th / nt;                               // expmap0 scale
    float pf = (th > MAXN) ? MAXN / th : 1.0f;        // proj scale (th>MAXN>0 safe)
    float hnc = fmaxf(fminf(th, MAXN), MINN);         // ||h|| after proj
    float ls = artanh_clip(hnc) / hnc;                // logmap0 scale
    float su = ls * pf * es;
    float u0 = fminf(fmaxf(su * tx, 0.0f), MAX_NORM); // relu + clamp
    float u1 = fminf(fmaxf(su * ty, 0.0f), MAX_NORM);
    // final expmap0
    float un = fmaxf(sqrtf(wave_sum(u0 * u0 + u1 * u1)), MINN);
    float os = tanhf(un) / un;
    float2 o; o.x = os * u0; o.y = os * u1;
    ((float2*)(OUT + (size_t)row * D))[lane] = o;
}

extern "C" void kernel_launch(void* const* d_in, const int* in_sizes, int n_in,
                              void* d_out, int out_size, void* d_ws, size_t ws_size,
                              hipStream_t stream)
{
    const float* x    = (const float*)d_in[0];
    const float* adj  = (const float*)d_in[1];
    const float* W    = (const float*)d_in[2];
    const float* bias = (const float*)d_in[3];
    const int*   erow = (const int*)d_in[4];
    const int*   ecol = (const int*)d_in[5];
    float* out = (float*)d_out;
    const int N = in_sizes[0] / D;   // 50000 (< 65536: col fits 16 bits in bpack)
    const int E = in_sizes[1];

    // workspace layout (256B aligned segments)
    char* p = (char*)d_ws;
    size_t off = 0;
    auto alloc = [&](size_t bytes) {
        char* r = p + off;
        off = (off + bytes + 255) & ~(size_t)255;
        return r;
    };
    ushort* xt  = (ushort*)alloc((size_t)N * D * sizeof(ushort));
    uint4*  wf  = (uint4*) alloc(2048 * sizeof(uint4));   // swizzled W frags
    int*   cnt  = (int*)  alloc((size_t)N * sizeof(int));
    int*   offs = (int*)  alloc((size_t)N * sizeof(int));
    int*   bsum = (int*)  alloc(256 * sizeof(int));
    int*   rank = (int*)  alloc((size_t)E * sizeof(int));
    uint*  bpack= (uint*) alloc((size_t)E * sizeof(uint));
    (void)ws_size;

    hipMemsetAsync(cnt, 0, (size_t)N * sizeof(int), stream);
    wconv_kernel<<<8, 256, 0, stream>>>(W, wf);
    gemm_mfma_kernel<<<(N + 31) / 32, 128, 0, stream>>>(x, wf, bias, xt, N);
    int E4 = E >> 2;
    hist_kernel<<<(E4 + 255) / 256, 256, 0, stream>>>(erow, cnt, rank, E);
    int nb = (N + 1023) / 1024;   // 49 for N=50000, must be <= 64
    scan1_kernel<<<nb, 256, 0, stream>>>(cnt, offs, bsum, N);
    scan2_kernel<<<1, 64, 0, stream>>>(bsum, nb);
    fill_kernel<<<(E4 + 255) / 256, 256, 0, stream>>>(erow, ecol, adj, rank, offs, bsum, bpack, E);
    gather_kernel<<<(N + 3) / 4, 256, 0, stream>>>(xt, bpack, offs, bsum, cnt, out, N);
}

// Round 8
// 117.294 us; speedup vs baseline: 12.2891x; 1.0155x over previous
//
#include <hip/hip_runtime.h>

#define D 128
#define MAXN 0.996f            // (1 - BALL_EPS) / sqrt(c), c = 1
#define MINN 1e-15f
#define ARTANH_MAX (1.0f - 1e-7f)
#define MAX_NORM 1e6f

typedef unsigned int uint;
typedef unsigned short ushort;
typedef __bf16 bf16x8 __attribute__((ext_vector_type(8)));
typedef float f32x4 __attribute__((ext_vector_type(4)));

__device__ __forceinline__ float wave_sum(float v) {
#pragma unroll
    for (int o = 32; o > 0; o >>= 1) v += __shfl_xor(v, o, 64);
    return v;
}

__device__ __forceinline__ float quad_sum(float v) {   // sum lanes l, l^16, l^32, l^48
    v += __shfl_xor(v, 16, 64);
    v += __shfl_xor(v, 32, 64);
    return v;
}

__device__ __forceinline__ float artanh_clip(float x) {
    x = fminf(fmaxf(x, -ARTANH_MAX), ARTANH_MAX);
    return 0.5f * logf((1.0f + x) / (1.0f - x));
}

__device__ __forceinline__ ushort f2bf(float f) {   // RNE, finite inputs
    uint u = __float_as_uint(f);
    return (ushort)((u + 0x7fffu + ((u >> 16) & 1u)) >> 16);
}

__device__ __forceinline__ uint pk2(float a, float b) {
    return (uint)f2bf(a) | ((uint)f2bf(b) << 16);
}

// ---- W fp32 -> bf16 A-frag swizzle (blocks 0-7) + cnt zeroing (all blocks) ----
// WF[(ks*8 + t)*64 + l] = 16B frag: W[t*16+lr][ks*32+kg*4 ..+3 , +16..+19], lr=l&15, kg=l>>4
__global__ __launch_bounds__(256)
void wconv_kernel(const float* __restrict__ W, uint4* __restrict__ WF,
                  int4* __restrict__ cnt4, int n4)
{
    int idx = blockIdx.x * 256 + threadIdx.x;
    if (idx < 2048) {
        int l = idx & 63, rest = idx >> 6;
        int t = rest & 7, ks = rest >> 3;
        int lr = l & 15, kg = l >> 4;
        const float* wrow = W + (size_t)(t * 16 + lr) * D + ks * 32 + kg * 4;
        float4 lo = *(const float4*)(wrow);
        float4 hi = *(const float4*)(wrow + 16);
        WF[idx] = make_uint4(pk2(lo.x, lo.y), pk2(lo.z, lo.w),
                             pk2(hi.x, hi.y), pk2(hi.z, hi.w));
    }
    // zero cnt (replaces 44us rocclr fillBuffer)
    for (int z = idx; z < n4; z += gridDim.x * 256)
        cnt4[z] = make_int4(0, 0, 0, 0);
}

// ---- MFMA GEMM + fused HypLinear: xt[m][:] = A_m*(x_m @ W^T) + B_m*b_hyp, bf16 out ----
// Per wave: 16 X-rows. A-frag = pre-swizzled W (coalesced uint4), B-frag = X rows (cvt).
// C/D map: Dcol j = lane&15 (X row), Drow i = (lane>>4)*4 + reg  [verified R5].
__global__ __launch_bounds__(128)
void gemm_mfma_kernel(const float* __restrict__ X, const uint4* __restrict__ WF,
                      const float* __restrict__ bias, ushort* __restrict__ XT, int N)
{
    const int wid = threadIdx.x >> 6;
    const int l   = threadIdx.x & 63;
    const int m0  = (blockIdx.x * 2 + wid) * 16;
    if (m0 >= N) return;
    const int lr = l & 15;          // X row within tile == D col j
    const int kg = l >> 4;          // k-group
    const int row = m0 + lr;
    const int rowc = row < N ? row : N - 1;

    // ---- B-frags (X rows) + ||x_row||^2 partial ----
    const float* xp = X + (size_t)rowc * D + kg * 4;
    bf16x8 bfr[4];
    float xsq = 0.f;
#pragma unroll
    for (int ks = 0; ks < 4; ++ks) {
        float4 v0 = *(const float4*)(xp + ks * 32);
        float4 v1 = *(const float4*)(xp + ks * 32 + 16);
        xsq += v0.x*v0.x + v0.y*v0.y + v0.z*v0.z + v0.w*v0.w
             + v1.x*v1.x + v1.y*v1.y + v1.z*v1.z + v1.w*v1.w;
        uint4 bq = make_uint4(pk2(v0.x, v0.y), pk2(v0.z, v0.w),
                              pk2(v1.x, v1.y), pk2(v1.z, v1.w));
        bfr[ks] = __builtin_bit_cast(bf16x8, bq);
    }
    xsq = quad_sum(xsq);            // full ||x_row||^2, row = m0+lr

    // ---- MFMA main: per ks, 8 batched coalesced A-frag loads then 8 MFMAs ----
    f32x4 acc[8];
#pragma unroll
    for (int t = 0; t < 8; ++t) acc[t] = (f32x4){0.f, 0.f, 0.f, 0.f};
#pragma unroll
    for (int ks = 0; ks < 4; ++ks) {
        uint4 wv[8];
#pragma unroll
        for (int t = 0; t < 8; ++t) wv[t] = WF[(ks * 8 + t) * 64 + l];
#pragma unroll
        for (int t = 0; t < 8; ++t)
            acc[t] = __builtin_amdgcn_mfma_f32_16x16x32_bf16(
                __builtin_bit_cast(bf16x8, wv[t]), bfr[ks], acc[t], 0, 0, 0);
    }

    // ---- bias values for this lane's output cols: n = t*16 + kg*4 + r ----
    float4 bb[8];
    float bsq = 0.f;
#pragma unroll
    for (int t = 0; t < 8; ++t) {
        bb[t] = *(const float4*)(bias + t * 16 + kg * 4);
        bsq += bb[t].x*bb[t].x + bb[t].y*bb[t].y + bb[t].z*bb[t].z + bb[t].w*bb[t].w;
    }
    bsq = quad_sum(bsq);            // ||bias||^2 (replicated)
    float bn  = fmaxf(sqrtf(bsq), MINN);
    float bt  = tanhf(bn);
    float bps = (bt > MAXN) ? MAXN / fmaxf(bt, MINN) : 1.0f;
    float bsc = bt / bn * bps;      // b_hyp = bsc * bias
    float bhn = fminf(fmaxf(bt * bps, MINN), MAXN);
    float y2  = bhn * bhn;

    // ---- row reductions: ||mx||^2 and <mx, bias> ----
    float sacc = 0.f, sab = 0.f;
#pragma unroll
    for (int t = 0; t < 8; ++t) {
        sacc += acc[t][0]*acc[t][0] + acc[t][1]*acc[t][1] + acc[t][2]*acc[t][2] + acc[t][3]*acc[t][3];
        sab  += acc[t][0]*bb[t].x + acc[t][1]*bb[t].y + acc[t][2]*bb[t].z + acc[t][3]*bb[t].w;
    }
    sacc = quad_sum(sacc);
    sab  = quad_sum(sab);

    // ---- HypLinear scalar tail (per output row) ----
    float xn  = fmaxf(sqrtf(xsq), MINN);
    float mxn = fmaxf(sqrtf(sacc), MINN);
    float t1  = tanhf(mxn / xn * artanh_clip(xn));    // ||res||
    float s1  = t1 / mxn;
    float ps1 = (t1 > MAXN) ? MAXN / fmaxf(t1, MINN) : 1.0f;
    float s1p = s1 * ps1;
    float rn  = fminf(fmaxf(t1, MINN), MAXN);
    float x2  = rn * rn;
    float mxb = bsc * sab;
    float xy  = s1p * mxb;
    float ca  = 1.0f + 2.0f * xy + y2;
    float cb  = 1.0f - x2;
    float den = fmaxf(1.0f + 2.0f * xy + x2 * y2, MINN);
    float alpha = ca * s1p / den;
    float beta  = cb / den;
    float hn2 = alpha * alpha * sacc + 2.0f * alpha * beta * mxb + beta * beta * y2;
    float hn  = fmaxf(sqrtf(hn2), MINN);
    float ps2 = (hn > MAXN) ? MAXN / hn : 1.0f;
    float hnc = fmaxf(fminf(hn, MAXN), MINN);
    float ls  = artanh_clip(hnc) / hnc;
    float F   = ls * ps2;
    float A = F * alpha, Bc = F * beta * bsc;

    if (row < N) {
        ushort* op = XT + (size_t)row * D + kg * 4;
#pragma unroll
        for (int t = 0; t < 8; ++t) {
            uint2 o = make_uint2(pk2(A * acc[t][0] + Bc * bb[t].x, A * acc[t][1] + Bc * bb[t].y),
                                 pk2(A * acc[t][2] + Bc * bb[t].z, A * acc[t][3] + Bc * bb[t].w));
            *(uint2*)(op + t * 16) = o;
        }
    }
}

// ---------------- CSR build ----------------
// hist (x4 vectorized): records each edge's arrival rank within its row
__global__ __launch_bounds__(256)
void hist_kernel(const int* __restrict__ erow, int* __restrict__ cnt,
                 int* __restrict__ rank, int E)
{
    int e4 = blockIdx.x * 256 + threadIdx.x;
    int E4 = E >> 2;
    if (e4 < E4) {
        int4 r = ((const int4*)erow)[e4];
        int4 k;
        k.x = atomicAdd(&cnt[r.x], 1);
        k.y = atomicAdd(&cnt[r.y], 1);
        k.z = atomicAdd(&cnt[r.z], 1);
        k.w = atomicAdd(&cnt[r.w], 1);
        ((int4*)rank)[e4] = k;
    }
    if (e4 == 0) {
        for (int i = E4 * 4; i < E; ++i) rank[i] = atomicAdd(&cnt[erow[i]], 1);
    }
}

// block-level partial exclusive scan: 1024 elems/block (256 thr x 4)
__global__ __launch_bounds__(256)
void scan1_kernel(const int* __restrict__ cnt, int* __restrict__ offs,
                  int* __restrict__ bsum, int N)
{
    __shared__ int wsum[4];
    int t = threadIdx.x;
    int base = blockIdx.x * 1024 + t * 4;
    int v[4];
#pragma unroll
    for (int j = 0; j < 4; ++j) v[j] = (base + j < N) ? cnt[base + j] : 0;
    int tt = v[0] + v[1] + v[2] + v[3];
    int incl = tt;
#pragma unroll
    for (int o = 1; o < 64; o <<= 1) {
        int n = __shfl_up(incl, o, 64);
        if ((t & 63) >= o) incl += n;
    }
    if ((t & 63) == 63) wsum[t >> 6] = incl;
    __syncthreads();
    int wbase = 0;
    for (int w = 0; w < (t >> 6); ++w) wbase += wsum[w];
    int ex = wbase + incl - tt;
#pragma unroll
    for (int j = 0; j < 4; ++j) {
        if (base + j < N) offs[base + j] = ex;
        ex += v[j];
    }
    if (t == 255) bsum[blockIdx.x] = wbase + incl;
}

__global__ __launch_bounds__(64)
void scan2_kernel(int* __restrict__ bsum, int nb)
{
    int l = threadIdx.x;
    int v = (l < nb) ? bsum[l] : 0;
    int incl = v;
#pragma unroll
    for (int o = 1; o < 64; o <<= 1) {
        int n = __shfl_up(incl, o, 64);
        if (l >= o) incl += n;
    }
    if (l < nb) bsum[l] = incl - v;
}

// atomic-free fill (x4 vectorized): p = offs[row]+bsum[chunk]+rank; 4B edge (col16|val-bf16)
__global__ __launch_bounds__(256)
void fill_kernel(const int* __restrict__ erow, const int* __restrict__ ecol,
                 const float* __restrict__ adj, const int* __restrict__ rank,
                 const int* __restrict__ offs, const int* __restrict__ bsum,
                 uint* __restrict__ bpack, int E)
{
    int e4 = blockIdx.x * 256 + threadIdx.x;
    int E4 = E >> 2;
    if (e4 < E4) {
        int4   r = ((const int4*)erow)[e4];
        int4   c = ((const int4*)ecol)[e4];
        float4 a = ((const float4*)adj)[e4];
        int4   k = ((const int4*)rank)[e4];
        bpack[offs[r.x] + bsum[r.x >> 10] + k.x] = ((uint)c.x << 16) | (uint)f2bf(a.x);
        bpack[offs[r.y] + bsum[r.y >> 10] + k.y] = ((uint)c.y << 16) | (uint)f2bf(a.y);
        bpack[offs[r.z] + bsum[r.z >> 10] + k.z] = ((uint)c.z << 16) | (uint)f2bf(a.z);
        bpack[offs[r.w] + bsum[r.w >> 10] + k.w] = ((uint)c.w << 16) | (uint)f2bf(a.w);
    }
    if (e4 == 0) {
        for (int i = E4 * 4; i < E; ++i) {
            int r = erow[i];
            bpack[offs[r] + bsum[r >> 10] + rank[i]] = ((uint)ecol[i] << 16) | (uint)f2bf(adj[i]);
        }
    }
}

// ------- gather (bf16 rows, 4B edges, 8-deep ILP) + fused HypAct tail (2 wave_sums) -------
__global__ __launch_bounds__(256)
void gather_kernel(const ushort* __restrict__ XT, const uint* __restrict__ bpack,
                   const int* __restrict__ offs, const int* __restrict__ bsum,
                   const int* __restrict__ cnt, float* __restrict__ OUT, int N)
{
    int row = blockIdx.x * 4 + (threadIdx.x >> 6);
    int lane = threadIdx.x & 63;
    if (row >= N) return;
    int start = offs[row] + bsum[row >> 10];
    int end = start + cnt[row];
    const uint* xtw = (const uint*)XT;   // 1 uint = 2 bf16 cols per lane
    float ax[8] = {0.f, 0.f, 0.f, 0.f, 0.f, 0.f, 0.f, 0.f};
    float ay[8] = {0.f, 0.f, 0.f, 0.f, 0.f, 0.f, 0.f, 0.f};
    int i = start;
    for (; i + 7 < end; i += 8) {
        uint4 qa = *(const uint4*)(bpack + i);       // wave-uniform 16B loads
        uint4 qb = *(const uint4*)(bpack + i + 4);
        uint q[8] = {qa.x, qa.y, qa.z, qa.w, qb.x, qb.y, qb.z, qb.w};
#pragma unroll
        for (int j = 0; j < 8; ++j) {
            uint u = xtw[(size_t)(q[j] >> 16) * 64 + lane];
            float v = __uint_as_float(q[j] << 16);
            ax[j] += v * __uint_as_float(u << 16);
            ay[j] += v * __uint_as_float(u & 0xffff0000u);
        }
    }
    for (; i + 3 < end; i += 4) {
        uint4 qa = *(const uint4*)(bpack + i);
        uint q[4] = {qa.x, qa.y, qa.z, qa.w};
#pragma unroll
        for (int j = 0; j < 4; ++j) {
            uint u = xtw[(size_t)(q[j] >> 16) * 64 + lane];
            float v = __uint_as_float(q[j] << 16);
            ax[j] += v * __uint_as_float(u << 16);
            ay[j] += v * __uint_as_float(u & 0xffff0000u);
        }
    }
    for (; i < end; ++i) {
        uint q = bpack[i];
        float v = __uint_as_float(q << 16);
        uint u = xtw[(size_t)(q >> 16) * 64 + lane];
        ax[0] += v * __uint_as_float(u << 16);
        ay[0] += v * __uint_as_float(u & 0xffff0000u);
    }
    float tx = ((ax[0] + ax[1]) + (ax[2] + ax[3])) + ((ax[4] + ax[5]) + (ax[6] + ax[7]));
    float ty = ((ay[0] + ay[1]) + (ay[2] + ay[3])) + ((ay[4] + ay[5]) + (ay[6] + ay[7]));
    tx = fminf(tx, MAX_NORM);
    ty = fminf(ty, MAX_NORM);
    // expmap0 + proj + logmap0 with analytic norms: ||expmap0(t)|| = tanh(||t||)
    float nt = fmaxf(sqrtf(wave_sum(tx * tx + ty * ty)), MINN);
    float th = tanhf(nt);
    float es = th / nt;                               // expmap0 scale
    float pf = (th > MAXN) ? MAXN / th : 1.0f;        // proj scale (th>MAXN>0 safe)
    float hnc = fmaxf(fminf(th, MAXN), MINN);         // ||h|| after proj
    float ls = artanh_clip(hnc) / hnc;                // logmap0 scale
    float su = ls * pf * es;
    float u0 = fminf(fmaxf(su * tx, 0.0f), MAX_NORM); // relu + clamp
    float u1 = fminf(fmaxf(su * ty, 0.0f), MAX_NORM);
    // final expmap0
    float un = fmaxf(sqrtf(wave_sum(u0 * u0 + u1 * u1)), MINN);
    float os = tanhf(un) / un;
    float2 o; o.x = os * u0; o.y = os * u1;
    ((float2*)(OUT + (size_t)row * D))[lane] = o;
}

extern "C" void kernel_launch(void* const* d_in, const int* in_sizes, int n_in,
                              void* d_out, int out_size, void* d_ws, size_t ws_size,
                              hipStream_t stream)
{
    const float* x    = (const float*)d_in[0];
    const float* adj  = (const float*)d_in[1];
    const float* W    = (const float*)d_in[2];
    const float* bias = (const float*)d_in[3];
    const int*   erow = (const int*)d_in[4];
    const int*   ecol = (const int*)d_in[5];
    float* out = (float*)d_out;
    const int N = in_sizes[0] / D;   // 50000 (< 65536: col fits 16 bits in bpack)
    const int E = in_sizes[1];

    // workspace layout (256B aligned segments)
    char* p = (char*)d_ws;
    size_t off = 0;
    auto alloc = [&](size_t bytes) {
        char* r = p + off;
        off = (off + bytes + 255) & ~(size_t)255;
        return r;
    };
    ushort* xt  = (ushort*)alloc((size_t)N * D * sizeof(ushort));
    uint4*  wf  = (uint4*) alloc(2048 * sizeof(uint4));   // swizzled W frags
    int*   cnt  = (int*)  alloc(((size_t)N + 4) * sizeof(int));
    int*   offs = (int*)  alloc((size_t)N * sizeof(int));
    int*   bsum = (int*)  alloc(256 * sizeof(int));
    int*   rank = (int*)  alloc((size_t)E * sizeof(int));
    uint*  bpack= (uint*) alloc((size_t)E * sizeof(uint));
    (void)ws_size;

    int n4 = (N + 3) >> 2;
    wconv_kernel<<<64, 256, 0, stream>>>(W, wf, (int4*)cnt, n4);
    gemm_mfma_kernel<<<(N + 31) / 32, 128, 0, stream>>>(x, wf, bias, xt, N);
    int E4 = E >> 2;
    hist_kernel<<<(E4 + 255) / 256, 256, 0, stream>>>(erow, cnt, rank, E);
    int nb = (N + 1023) / 1024;   // 49 for N=50000, must be <= 64
    scan1_kernel<<<nb, 256, 0, stream>>>(cnt, offs, bsum, N);
    scan2_kernel<<<1, 64, 0, stream>>>(bsum, nb);
    fill_kernel<<<(E4 + 255) / 256, 256, 0, stream>>>(erow, ecol, adj, rank, offs, bsum, bpack, E);
    gather_kernel<<<(N + 3) / 4, 256, 0, stream>>>(xt, bpack, offs, bsum, cnt, out, N);
}